// Round 3
// baseline (133.999 us; speedup 1.0000x reference)
//
#include <hip/hip_runtime.h>
#include <math.h>

#define L2P 1.8378770664093453f
#define TF 4
#define WUP 8

__device__ __forceinline__ void ld16(float* __restrict__ d, const float* __restrict__ p) {
  const float4 a = *(const float4*)(p);
  const float4 b = *(const float4*)(p + 4);
  const float4 cc = *(const float4*)(p + 8);
  const float4 e = *(const float4*)(p + 12);
  d[0] = a.x; d[1] = a.y; d[2] = a.z; d[3] = a.w;
  d[4] = b.x; d[5] = b.y; d[6] = b.z; d[7] = b.w;
  d[8] = cc.x; d[9] = cc.y; d[10] = cc.z; d[11] = cc.w;
  d[12] = e.x; d[13] = e.y; d[14] = e.z; d[15] = e.w;
}

__device__ __forceinline__ float dot16rr(const float* __restrict__ a,
                                         const float* __restrict__ b) {
  float s0 = 0.f, s1 = 0.f;
#pragma unroll
  for (int k = 0; k < 16; k += 2) {
    s0 = fmaf(a[k], b[k], s0);
    s1 = fmaf(a[k + 1], b[k + 1], s1);
  }
  return s0 + s1;
}

__device__ __forceinline__ float dotshfl16(const float* __restrict__ a, float v) {
  float s0 = 0.f, s1 = 0.f;
#pragma unroll
  for (int k = 0; k < 16; k += 2) {
    s0 = fmaf(a[k], __shfl(v, k, 16), s0);
    s1 = fmaf(a[k + 1], __shfl(v, k + 1, 16), s1);
  }
  return s0 + s1;
}

// Wave-local 8-pivot block-GJ phase on a 16x32 augmented system (SPD).
// ONE wave handles the whole system, 8 rows per lane; full output store.
// In-wave ds_write->ds_read ordering (lgkmcnt) replaces __syncthreads.
__device__ __forceinline__ float gjw_phase(const float* __restrict__ X,
                                           float* __restrict__ Y, int k, int lane) {
  const int ca = lane & 31;
  const int r8 = (lane >> 5) * 8;
  float p[8][8];
#pragma unroll
  for (int i = 0; i < 8; ++i) {
    const float4 v0 = *(const float4*)&X[(k + i) * 32 + k];
    const float4 v1 = *(const float4*)&X[(k + i) * 32 + k + 4];
    p[i][0] = v0.x; p[i][1] = v0.y; p[i][2] = v0.z; p[i][3] = v0.w;
    p[i][4] = v1.x; p[i][5] = v1.y; p[i][6] = v1.z; p[i][7] = v1.w;
  }
  float rhs[8];
#pragma unroll
  for (int i = 0; i < 8; ++i) rhs[i] = X[(k + i) * 32 + ca];
  float det = 1.f;
#pragma unroll
  for (int i = 0; i < 8; ++i) {
    det *= p[i][i];
    const float ip = __builtin_amdgcn_rcpf(p[i][i]);
#pragma unroll
    for (int j = i + 1; j < 8; ++j) p[i][j] *= ip;
    rhs[i] *= ip;
#pragma unroll
    for (int m2 = i + 1; m2 < 8; ++m2) {
      const float f = p[m2][i];
#pragma unroll
      for (int j = i + 1; j < 8; ++j) p[m2][j] = fmaf(-f, p[i][j], p[m2][j]);
      rhs[m2] = fmaf(-f, rhs[i], rhs[m2]);
    }
  }
  float w[8];
#pragma unroll
  for (int i = 7; i >= 0; --i) {
    float s = rhs[i];
#pragma unroll
    for (int j = i + 1; j < 8; ++j) s = fmaf(-p[i][j], w[j], s);
    w[i] = s;
  }
#pragma unroll
  for (int h = 0; h < 8; ++h) {
    const int rr = r8 + h;
    float o;
    if (rr >= k && rr < k + 8) {
      o = w[rr - k];
    } else {
      const float4 s0 = *(const float4*)&X[rr * 32 + k];
      const float4 s1 = *(const float4*)&X[rr * 32 + k + 4];
      o = X[rr * 32 + ca] -
          (s0.x * w[0] + s0.y * w[1] + s0.z * w[2] + s0.w * w[3] +
           s1.x * w[4] + s1.y * w[5] + s1.z * w[6] + s1.w * w[7]);
    }
    Y[rr * 32 + ca] = o;
  }
  return det;
}

// Second GJ phase (k=8 hardcoded) storing ONLY the inverse half, scaled,
// directly to a 16x16 r-major destination. Bitwise-identical values.
__device__ __forceinline__ float gjw_store(const float* __restrict__ X,
                                           float* __restrict__ dst, float scale,
                                           int lane) {
  const int ca = lane & 31;
  const int r8 = (lane >> 5) * 8;
  float p[8][8];
#pragma unroll
  for (int i = 0; i < 8; ++i) {
    const float4 v0 = *(const float4*)&X[(8 + i) * 32 + 8];
    const float4 v1 = *(const float4*)&X[(8 + i) * 32 + 12];
    p[i][0] = v0.x; p[i][1] = v0.y; p[i][2] = v0.z; p[i][3] = v0.w;
    p[i][4] = v1.x; p[i][5] = v1.y; p[i][6] = v1.z; p[i][7] = v1.w;
  }
  float rhs[8];
#pragma unroll
  for (int i = 0; i < 8; ++i) rhs[i] = X[(8 + i) * 32 + ca];
  float det = 1.f;
#pragma unroll
  for (int i = 0; i < 8; ++i) {
    det *= p[i][i];
    const float ip = __builtin_amdgcn_rcpf(p[i][i]);
#pragma unroll
    for (int j = i + 1; j < 8; ++j) p[i][j] *= ip;
    rhs[i] *= ip;
#pragma unroll
    for (int m2 = i + 1; m2 < 8; ++m2) {
      const float f = p[m2][i];
#pragma unroll
      for (int j = i + 1; j < 8; ++j) p[m2][j] = fmaf(-f, p[i][j], p[m2][j]);
      rhs[m2] = fmaf(-f, rhs[i], rhs[m2]);
    }
  }
  float w[8];
#pragma unroll
  for (int i = 7; i >= 0; --i) {
    float s = rhs[i];
#pragma unroll
    for (int j = i + 1; j < 8; ++j) s = fmaf(-p[i][j], w[j], s);
    w[i] = s;
  }
  const bool st = (ca >= 16);
  const int cd = ca - 16;
#pragma unroll
  for (int h = 0; h < 8; ++h) {
    const int rr = r8 + h;
    float o;
    if (rr >= 8) {
      o = w[rr - 8];
    } else {
      const float4 s0 = *(const float4*)&X[rr * 32 + 8];
      const float4 s1 = *(const float4*)&X[rr * 32 + 12];
      o = X[rr * 32 + ca] -
          (s0.x * w[0] + s0.y * w[1] + s0.z * w[2] + s0.w * w[3] +
           s1.x * w[4] + s1.y * w[5] + s1.z * w[6] + s1.w * w[7]);
    }
    if (st) dst[rr * 16 + cd] = scale * o;
  }
  return det;
}

extern "C" __global__ __launch_bounds__(512, 1) void lgq_kernel(
    const float* __restrict__ g_obs, const float* __restrict__ g_ppm,
    const float* __restrict__ g_ppc, const float* __restrict__ g_ptw,
    const float* __restrict__ g_ptb, const float* __restrict__ g_ptc,
    const float* __restrict__ g_pew, const float* __restrict__ g_peb,
    const float* __restrict__ g_pec, const float* __restrict__ g_qpm,
    const float* __restrict__ g_qpc, const float* __restrict__ g_qtw,
    const float* __restrict__ g_qtb, const float* __restrict__ g_qtc,
    const float* __restrict__ g_qew, const float* __restrict__ g_qeb,
    const float* __restrict__ g_qec, float* __restrict__ out) {
  const int tid = threadIdx.x;
  const bool lo = tid < 256;
  const int t8 = tid & 255;
  const int r = t8 >> 4, c = tid & 15;
  const int hf = tid >> 8;
  const int wv = tid >> 6;
  const int lane = tid & 63;

  __shared__ __align__(16) float obs_s[4096];  // reused as w_t after exact loop
  __shared__ __align__(16) float hyb[4096];    // aliased as aug6A in preamble
  __shared__ __align__(16) float eoy[4096];    // aliased as aug6B; becomes eu
  __shared__ float qOmO[256];
  __shared__ float ring[32];
  __shared__ __align__(16) float augA[512], augB[512], augN[512];
  __shared__ __align__(16) float bcovC[256], fcInv[256];
  __shared__ __align__(16) float Wq[256], Hq[256], Wp[256], We[256];
  __shared__ __align__(16) float qtp[256], Rinv[256], Qp0i[256];
  __shared__ __align__(16) float ct[256], M0[256], Eq[256], Eo[256], c3m[256];
  __shared__ __align__(16) float OmT[256], OmO[256], Om0[256];
  __shared__ __align__(16) float F0[256], W2n[256], Tt[256];
  __shared__ __align__(16) float S0[256], S1[256];
  __shared__ __align__(16) float bAT[320], t1T[320], Emat[256], fprec[256];
  __shared__ __align__(16) float bAfN[256], A0fN[256], A0fT[320];
  __shared__ __align__(16) float ctT[320], WeT[320], Dm[256];
  __shared__ __align__(16) float R1m[256], R1T[320], R2m[256], R2T[320];
  __shared__ __align__(16) float T1m[256], T2m[256];
  __shared__ __align__(16) float BkA[256], BkAT[320], BkB[256], BkBT[320];
  __shared__ __align__(16) float hA256[256], hB256[256];
  __shared__ __align__(16) float eta[16], ba[16], u_t[16], zv[16];
  __shared__ __align__(16) float gb0[16], gb1[16], fm[16];
  __shared__ __align__(16) float etaF[16], gfin[16];
  __shared__ float qtb[16], dqv[16], ptb[16], peb[16], ppmv[16], qpmv[16];
  __shared__ float v0[16], u0[16], wc_s[16], uc_s[16], vta[16], bau0v[16];
  __shared__ float scl[8];
  __shared__ float cB_s;

  float* aug6A = hyb;
  float* aug6B = eoy;

  // ---- phase 0: loads + 6 wave-parallel inversions with direct store ----
#pragma unroll
  for (int j = 0; j < 8; ++j) obs_s[tid + 512 * j] = g_obs[tid + 512 * j];

  float trace_acc = 0.f, hacc = 0.f;

  if (wv < 6) {
    const float* M = (wv == 0) ? g_ptc : (wv == 1) ? g_pec : (wv == 2) ? g_qtc
                     : (wv == 3) ? g_qec : (wv == 4) ? g_ppc : g_qpc;
    float* A = aug6A + wv * 512;
    float* Bp = aug6B + wv * 512;
    const int ca = lane & 31;
    const int r8 = (lane >> 5) * 8;
#pragma unroll
    for (int h = 0; h < 8; ++h) {
      const int rr = r8 + h;
      A[rr * 32 + ca] = (ca < 16) ? M[rr * 16 + ca] : ((rr == ca - 16) ? 1.f : 0.f);
    }
    const float d0 = gjw_phase(A, Bp, 0, lane);
    float* dst = (wv == 0) ? OmT : (wv == 1) ? OmO : (wv == 2) ? qtp
                 : (wv == 3) ? Rinv : (wv == 4) ? Om0 : Qp0i;
    const float scale = (wv == 2 || wv == 3 || wv == 5) ? 1.0f : -0.5f;
    const float d1 = gjw_store(Bp, dst, scale, lane);
    if (lane == 0) { ring[wv * 2] = d0; ring[wv * 2 + 1] = d1; }
  } else if (wv == 6) {
    if (lane < 16) {
      qtb[lane] = g_qtb[lane];
      dqv[lane] = g_qeb[lane];
      ptb[lane] = g_ptb[lane];
      peb[lane] = g_peb[lane];
    } else if (lane < 32) {
      const int i = lane - 16;
      ppmv[i] = g_ppm[i];
      qpmv[i] = g_qpm[i];
    }
  } else {  // wv == 7
#pragma unroll
    for (int j = 0; j < 4; ++j) {
      const int i = lane + 64 * j;
      Wq[i] = g_qtw[i];
      Hq[i] = g_qew[i];
      Wp[i] = g_ptw[i];
      We[i] = g_pew[i];
    }
  }

  // ---- mmA (512-split): ct,Eq | Tt,Eo ----
  __syncthreads();
  if (!hf) {
    float a = 0.f, b = 0.f;
#pragma unroll
    for (int k = 0; k < 16; ++k) {
      a = fmaf(Wq[k * 16 + r], qtp[k * 16 + c], a);
      b = fmaf(Hq[k * 16 + r], Rinv[k * 16 + c], b);
    }
    ct[t8] = a;
    Eq[t8] = b;
  } else {
    float d = 0.f, e = 0.f;
#pragma unroll
    for (int k = 0; k < 16; ++k) {
      d = fmaf(OmT[r * 16 + k], Wp[k * 16 + c], d);
      e = fmaf(We[k * 16 + r], OmO[k * 16 + c], e);
    }
    Tt[t8] = d;
    Eo[t8] = e;
  }

  // ---- fused: batch per-t vectors + mmBCD (both 512-split) ----
  __syncthreads();
  {
    float ym[16], ob[16];
#pragma unroll
    for (int k = 0; k < 16; ++k) {
      const float y = obs_s[t8 * 16 + k];
      ym[k] = y - dqv[k];
      ob[k] = peb[k] - y;
    }
    const int i0 = hf * 8;
#pragma unroll
    for (int i2 = 0; i2 < 8; ++i2) {
      const int i = i0 + i2;
      float a = 0.f, b = 0.f;
#pragma unroll
      for (int k = 0; k < 16; ++k) {
        a = fmaf(Eq[i * 16 + k], ym[k], a);
        b = fmaf(Eo[i * 16 + k], ob[k], b);
      }
      hyb[t8 * 16 + i] = a;
      eoy[t8 * 16 + i] = b;
    }
    if (hf) {
      float q = 0.f;
#pragma unroll
      for (int i = 0; i < 16; ++i) {
        float d = 0.f;
#pragma unroll
        for (int k = 0; k < 16; ++k) d = fmaf(OmO[i * 16 + k], ob[k], d);
        q = fmaf(ob[i], d, q);
      }
      qOmO[t8] = q;
    }
  }
  if (!hf) {
    float a = 0.f, b = 0.f;
#pragma unroll
    for (int k = 0; k < 16; ++k) {
      a = fmaf(ct[r * 16 + k], Wq[k * 16 + c], a);
      b = fmaf(Eq[r * 16 + k], Hq[k * 16 + c], b);
    }
    M0[t8] = a;
    F0[t8] = qtp[t8] + b;
    fprec[t8] = Qp0i[t8] + b;
    if (tid < 16) {
      float s = 0.f;
#pragma unroll
      for (int k = 0; k < 16; ++k) s = fmaf(ct[tid * 16 + k], qtb[k], s);
      u0[tid] = s;
    } else if (tid < 32) {
      const int i = tid - 16;
      float s = 0.f;
#pragma unroll
      for (int k = 0; k < 16; ++k) s = fmaf(qtp[i * 16 + k], qtb[k], s);
      v0[i] = s;
    } else if (tid < 48) {
      const int i = tid - 32;
      float s = 0.f;
#pragma unroll
      for (int k = 0; k < 16; ++k) s = fmaf(Om0[i * 16 + k], ppmv[k], s);
      vta[i] = s;
    } else if (tid < 64) {
      const int i = tid - 48;
      float s = 0.f;
#pragma unroll
      for (int k = 0; k < 16; ++k) s = fmaf(Tt[k * 16 + i], ptb[k], s);
      wc_s[i] = s;
    } else if (tid < 80) {
      const int i = tid - 64;
      float s = 0.f;
#pragma unroll
      for (int k = 0; k < 16; ++k) s = fmaf(OmT[i * 16 + k], ptb[k], s);
      uc_s[i] = s;
    }
  } else {
    float e = 0.f, co = 0.f;
#pragma unroll
    for (int k = 0; k < 16; ++k) {
      e = fmaf(Wp[k * 16 + r], Tt[k * 16 + c], e);
      co = fmaf(Eo[r * 16 + k], We[k * 16 + c], co);
    }
    W2n[t8] = e;
    S0[t8] = Om0[t8] + co + e;   // Sw_1
    c3m[t8] = OmT[t8] + co + e;  // c3
  }

  // ---- mmE: eta0/gb0/cB/hacc init ; register constants ; fill augN ----
  // loop-phase-B registers use COLUMN-major mapping (cc2 = tid>>4, rr2 = tid&15)
  const int cc2 = t8 >> 4;   // column owned in loop phase B (same as r index)
  const int rr2 = tid & 15;  // row owned in loop phase B (same as c index)
  float ctc2[16], ctr2[16], ttr2[16];
  float f0_rc, d0_rc, c3_rc;
  __syncthreads();
  if (lo) {
    if (tid < 16) {
      float s = hyb[tid];
#pragma unroll
      for (int k = 0; k < 16; ++k) s = fmaf(Qp0i[tid * 16 + k], qpmv[k], s);
      eta[tid] = s;
      hacc += ppmv[tid] * vta[tid];
    } else if (tid < 32) {
      const int i = tid - 16;
      gb0[i] = eoy[i] - vta[i];
    }
    if (tid == 0) {
      float s = 0.f;
#pragma unroll
      for (int k = 0; k < 16; ++k) s = fmaf(ptb[k], uc_s[k], s);
      cB_s = s;
      hacc += qOmO[0];
    }
#pragma unroll
    for (int k = 0; k < 16; ++k) {
      ctc2[k] = ct[k * 16 + cc2];
      ctr2[k] = ct[k * 16 + rr2];
      ttr2[k] = Tt[rr2 * 16 + k];
    }
    const int e = rr2 * 16 + cc2;
    f0_rc = F0[e];
    d0_rc = M0[e] + F0[e];
    c3_rc = c3m[tid];  // r-major; used only in transition phase
    augN[rr2 * 32 + cc2] = M0[e] + fprec[e];
    augN[rr2 * 32 + 16 + cc2] = (rr2 == cc2) ? 1.f : 0.f;
  }

  float* Scur = S0;
  float* Snxt = S1;
  float* gcur = gb0;
  float* gnxt = gb1;

  // ================= exact forward t = 1..TF : 2 phases/step =============
#pragma unroll 1
  for (int t = 1; t <= TF; ++t) {
    const int rb = 12 + (t - 1) * 2;
    // ---- phase A: wave0 double-GJ + ba ; wave4 Snxt ; wave5 gnxt ----
    __syncthreads();
    if (wv == 0) {
      const float det0 = gjw_phase(augN, augB, 0, lane);
      const float det1 = gjw_store(augB, bcovC, 1.0f, lane);
      if (lane == 0) { ring[rb] = det0; ring[rb + 1] = det1; }
      if (lane < 16) {
        float bc[16]; ld16(bc, &bcovC[lane * 16]);
        float a2 = 0.f;
#pragma unroll
        for (int k = 0; k < 16; ++k) a2 = fmaf(bc[k], eta[k] - u0[k], a2);
        ba[lane] = a2;
      }
    } else if (wv == 4 && t > 1) {
      const int ec = lane & 15, er0 = lane >> 4;
      float t1c[16]; ld16(t1c, &t1T[ec * 20]);
#pragma unroll
      for (int q = 0; q < 4; ++q) {
        const int er = er0 + 4 * q;
        const int e = er * 16 + ec;
        float btr[16]; ld16(btr, &bAT[er * 20]);
        Snxt[e] = dot16rr(btr, t1c) - Emat[er * 16 + ec] - Emat[ec * 16 + er] + c3m[e];
      }
    } else if (wv == 5 && t > 1) {
      if (lane < 16) {
        float bti[16]; ld16(bti, &bAT[lane * 20]);
        float zvv[16]; ld16(zvv, zv);
        gnxt[lane] = -u_t[lane] + eoy[(t - 1) * 16 + lane] + dot16rr(bti, zvv);
      }
    }
    if (t > 1) {
      float* tp = Scur; Scur = Snxt; Snxt = tp;
      tp = gcur; gcur = gnxt; gnxt = tp;
    }
    // ---- phase B: fused Q1+Q2 (column-major lo) ; wave5 eta/u_t/zv ;
    // ----          wave6 bau0v at t==TF ----
    __syncthreads();
    if (lo) {
      // Q1: bA[rr2][cc2]; column cc2 lives in THIS wave -> in-wave Q2 read
      float brow[16]; ld16(brow, &bcovC[rr2 * 16]);
      const float acc = dot16rr(brow, ctc2);
      bAT[cc2 * 20 + rr2] = acc;
      const float bce = bcovC[rr2 * 16 + cc2];
      const float sw_rc = Scur[rr2 * 16 + cc2];
      trace_acc = fmaf(bce, sw_rc, trace_acc);
      if (t == TF) bAfN[rr2 * 16 + cc2] = acc;
      // Q2 (reads bAT column cc2 written by same wave above)
      float bcol[16]; ld16(bcol, &bAT[cc2 * 20]);
      float swr[16];  ld16(swr, &Scur[rr2 * 16]);
      float a1 = 0.f, ae = 0.f, af = 0.f;
#pragma unroll
      for (int k = 0; k < 16; ++k) {
        a1 = fmaf(swr[k], bcol[k], a1);
        ae = fmaf(ttr2[k], bcol[k], ae);
        af = fmaf(ctr2[k], bcol[k], af);
      }
      t1T[cc2 * 20 + rr2] = a1;
      Emat[rr2 * 16 + cc2] = ae;
      fprec[rr2 * 16 + cc2] = f0_rc - af;
      augN[rr2 * 32 + cc2] = d0_rc - af;
      augN[rr2 * 32 + 16 + cc2] = (rr2 == cc2) ? 1.f : 0.f;
      if (t == TF) {
        float wpr[16]; ld16(wpr, &Wp[rr2 * 16]);
        float a0 = 0.f;
#pragma unroll
        for (int k = 0; k < 16; ++k) a0 = fmaf(wpr[k], bcol[k], a0);
        a0 -= (rr2 == cc2) ? 1.f : 0.f;
        A0fN[rr2 * 16 + cc2] = a0;
        A0fT[cc2 * 20 + rr2] = a0;
      }
      const float bar = ba[rr2], bac = ba[cc2];
      hacc = fmaf(bar * sw_rc, bac, hacc);
      if (rr2 == 0) hacc += 2.f * bac * (gcur[cc2] + wc_s[cc2]);
      if (tid == 0) hacc += cB_s + qOmO[t];
    } else if (wv == 5) {
      if (lane < 16) {
        const int i = lane;
        float e = v0[i] + hyb[t * 16 + i];
#pragma unroll
        for (int k = 0; k < 16; ++k) e = fmaf(ct[k * 16 + i], ba[k], e);
        eta[i] = e;
      } else if (lane < 32) {
        const int i = lane - 16;
        float ttrow[16]; ld16(ttrow, &Tt[i * 16]);
        float bav[16]; ld16(bav, ba);
        u_t[i] = uc_s[i] + dot16rr(ttrow, bav);
      } else if (lane < 48) {
        const int i = lane - 32;
        float swrow[16]; ld16(swrow, &Scur[i * 16]);
        float bav[16]; ld16(bav, ba);
        zv[i] = gcur[i] + wc_s[i] + dot16rr(swrow, bav);
      }
    } else if (wv == 6 && t == TF) {
      if (lane < 16) {
        float bc[16]; ld16(bc, &bcovC[lane * 16]);
        float u0v[16]; ld16(u0v, u0);
        bau0v[lane] = dot16rr(bc, u0v);
      }
    }
  }

  // ---- fused: transition (lo) + w/eu batch (hi 256, 16 outputs each) ----
  __syncthreads();
  if (lo) {
    float btr[16]; ld16(btr, &bAT[r * 20]);
    float t1c[16]; ld16(t1c, &t1T[c * 20]);
    Snxt[tid] = dot16rr(btr, t1c) - Emat[r * 16 + c] - Emat[c * 16 + r] + c3_rc;
    float bcr[16]; ld16(bcr, &bcovC[r * 16]);
    float ctrow[16]; ld16(ctrow, &ct[c * 16]);
    Dm[tid] = dot16rr(bcr, ctrow);  // D[r][c] = sum_k bcov[r][k] ct[c][k]
    ctT[c * 20 + r] = ct[tid];
    WeT[c * 20 + r] = We[tid];
  } else {
    float tmp[16];
#pragma unroll
    for (int k = 0; k < 16; ++k) tmp[k] = v0[k] + hyb[t8 * 16 + k];
#pragma unroll
    for (int i = 0; i < 16; ++i) {
      float s = -bau0v[i];
#pragma unroll
      for (int k = 0; k < 16; ++k) s = fmaf(bcovC[i * 16 + k], tmp[k], s);
      obs_s[t8 * 16 + i] = s;
    }
    if (t8 >= TF) {
#pragma unroll
      for (int i = 0; i < 16; ++i) eoy[t8 * 16 + i] -= uc_s[i];
    }
  }
  { float* tp = Scur; Scur = Snxt; Snxt = tp; }

  // ======= waves 0-3: steady-state chain t=TF+1..255 (16 chunks)
  // ======= wave 4: final fc inversion ; wave 5: S1 + Lyapunov (concurrent)
  __syncthreads();
  if (lo) {
    const int grp = tid >> 4;
    const int i = tid & 15;
    float drow[16], swr[16], ttr[16], bcol[16];
    ld16(drow, &Dm[i * 16]);   // D row i
    ld16(swr, &Scur[i * 16]);  // Sw* row i
    ld16(ttr, &Tt[i * 16]);    // Tt row i
    ld16(bcol, &bAT[i * 20]);  // B col i
    const float wci = wc_s[i];
    float ba_p, zv_p;
    if (grp == 0) {
      ba_p = ba[i]; zv_p = zv[i];
    } else {
      ba_p = 0.f; zv_p = 0.f;
    }
    float haccA = 0.f, haccB = 0.f;
    const int tstart = (TF + 1) + grp * 16 - WUP;
#pragma unroll 1
    for (int j = 0; j < WUP + 16; ++j) {
      if (grp == 0 && j < WUP) continue;
      const int t = tstart + j;
      const int trd = (t > 255) ? 255 : t;
      const float w_c = obs_s[(trd - 1) * 16 + i];
      const float eu_c = eoy[(trd - 1) * 16 + i];
      const float ban = dotshfl16(drow, ba_p) + w_c;
      const float q = dotshfl16(ttr, ba_p);
      const float bz = dotshfl16(bcol, zv_p);
      const float gnew = eu_c - q + bz;
      const float ssw = dotshfl16(swr, ban);
      if (j >= WUP && t <= 255) {
        haccA = fmaf(ban, ssw, haccA);
        haccB = fmaf(ban, gnew + wci, haccB);
      }
      if (t <= 255) {
        zv_p = gnew + wci + ssw;
        ba_p = ban;
      }
    }
    hA256[tid] = haccA;
    hB256[tid] = haccB;
    if (grp == 15) {
      // tail: g_256 = eu_255 - Tt ba_255 + B^T zv_255 ; eta_256
      const float eu_c = eoy[255 * 16 + i];
      gfin[i] = eu_c - dotshfl16(ttr, ba_p) + dotshfl16(bcol, zv_p);
      float ctcol[16]; ld16(ctcol, &ctT[i * 20]);
      etaF[i] = v0[i] + hyb[255 * 16 + i] + dotshfl16(ctcol, ba_p);
    }
  } else if (wv == 4) {
    // final fc = inv(fprec*): wave-local, 2 GJ phases, direct store
    const int ca = lane & 31;
    const int r8 = (lane >> 5) * 8;
#pragma unroll
    for (int h = 0; h < 8; ++h) {
      const int rr = r8 + h;
      augA[rr * 32 + ca] = (ca < 16) ? fprec[rr * 16 + ca] : ((rr == ca - 16) ? 1.f : 0.f);
    }
    const float d0 = gjw_phase(augA, augB, 0, lane);
    const float d1 = gjw_store(augB, fcInv, 1.0f, lane);
    if (lane == 0) { ring[12 + TF * 2] = d0; ring[12 + TF * 2 + 1] = d1; }
  } else if (wv == 5) {
    // S1 (R inits, Bk init) + 4x Lyapunov doubling, wave-local
    const int ec = lane & 15, er0 = lane >> 4;
    {
      float a0c[16]; ld16(a0c, &A0fT[ec * 20]);
      float wec[16]; ld16(wec, &WeT[ec * 20]);
#pragma unroll
      for (int q = 0; q < 4; ++q) {
        const int er = er0 + 4 * q;
        const int e = er * 16 + ec;
        float omtr[16]; ld16(omtr, &OmT[er * 16]);
        float omor[16]; ld16(omor, &OmO[er * 16]);
        const float c1 = dot16rr(omtr, a0c);
        R1m[e] = c1; R1T[ec * 20 + er] = c1;
        const float c2 = dot16rr(omor, wec);
        R2m[e] = c2; R2T[ec * 20 + er] = c2;
        BkA[e] = bAfN[e];
        BkAT[ec * 20 + er] = bAT[ec * 20 + er];
      }
    }
    float* pBk = BkA;  float* pBkT = BkAT;
    float* pBn = BkB;  float* pBnT = BkBT;
#pragma unroll 1
    for (int it = 0; it < 4; ++it) {
      {
        float r1c[16]; ld16(r1c, &R1T[ec * 20]);
        float r2c[16]; ld16(r2c, &R2T[ec * 20]);
        float bkc[16]; ld16(bkc, &pBkT[ec * 20]);
#pragma unroll
        for (int q = 0; q < 4; ++q) {
          const int er = er0 + 4 * q;
          const int e = er * 16 + ec;
          float bkr[16]; ld16(bkr, &pBk[er * 16]);
          T1m[e] = dot16rr(bkr, r1c);
          T2m[e] = dot16rr(bkr, r2c);
          const float bsq = dot16rr(bkr, bkc);
          pBn[e] = bsq;
          pBnT[ec * 20 + er] = bsq;
        }
      }
      {
        float bkc[16]; ld16(bkc, &pBkT[ec * 20]);
#pragma unroll
        for (int q = 0; q < 4; ++q) {
          const int er = er0 + 4 * q;
          const int e = er * 16 + ec;
          float t1r[16]; ld16(t1r, &T1m[er * 16]);
          float t2r[16]; ld16(t2r, &T2m[er * 16]);
          const float n1 = R1m[e] + dot16rr(t1r, bkc);
          const float n2 = R2m[e] + dot16rr(t2r, bkc);
          R1m[e] = n1; R1T[ec * 20 + er] = n1;
          R2m[e] = n2; R2T[ec * 20 + er] = n2;
        }
      }
      { float* tp = pBk; pBk = pBn; pBn = tp; }
      { float* tp = pBkT; pBkT = pBnT; pBnT = tp; }
    }
  }

  // ---- join: fm = fc * etaF ----
  __syncthreads();
  if (tid < 16) {
    float fr[16]; ld16(fr, &fcInv[tid * 16]);
    float ev[16]; ld16(ev, etaF);
    fm[tid] = dot16rr(fr, ev);
  }
  __syncthreads();

  // ---- final reduce & output (Z folded in) ----
  {
    float psum = 0.f;
    if (lo) {
      const float cnt = 255.f - (float)TF;
      psum = trace_acc + hacc;
      psum += cnt * bcovC[tid] * Scur[tid];
      {
        float a0rowc[16]; ld16(a0rowc, &A0fN[c * 16]);
        float r1colr[16]; ld16(r1colr, &R1T[r * 20]);
        float werowc[16]; ld16(werowc, &We[c * 16]);
        float r2colr[16]; ld16(r2colr, &R2T[r * 20]);
        const float zcr = dot16rr(a0rowc, r1colr) + dot16rr(werowc, r2colr);
        psum += fcInv[tid] * zcr;
      }
      psum += fm[r] * (Scur[tid] - W2n[tid]) * fm[c];
      if (r == 0) psum += 2.f * fm[c] * gfin[c];
      psum += hA256[tid] + 2.f * hB256[tid];
      if (tid > TF) psum += qOmO[tid];
      if (tid == 0) psum += cnt * cB_s;
#pragma unroll 1
      for (int i = tid; i < 12 + TF * 2 + 2; i += 256) {
        float w;
        if (i < 2) w = 255.f;
        else if (i < 4) w = 256.f;
        else if (i < 8) w = 0.f;
        else if (i < 10) w = 1.f;
        else if (i < 12) w = 0.f;
        else if (i < 12 + TF * 2) w = (i >= 12 + (TF - 1) * 2) ? (1.f + cnt) : 1.f;
        else w = 1.f;
        if (w != 0.f) psum -= 0.5f * w * logf(ring[i]);
      }
    }
#pragma unroll
    for (int off = 32; off; off >>= 1) psum += __shfl_down(psum, off, 64);
    if ((tid & 63) == 0) scl[tid >> 6] = psum;
  }
  __syncthreads();
  if (tid == 0) {
    const float base = -16.f * L2P + 255.f * (8.f - 8.f * L2P) + 8.f * L2P + 8.f;
    out[0] = scl[0] + scl[1] + scl[2] + scl[3] + scl[4] + scl[5] + scl[6] + scl[7] + base;
  }
}

extern "C" void kernel_launch(void* const* d_in, const int* in_sizes, int n_in,
                              void* d_out, int out_size, void* d_ws, size_t ws_size,
                              hipStream_t stream) {
  (void)in_sizes; (void)n_in; (void)out_size; (void)d_ws; (void)ws_size;
  lgq_kernel<<<1, 512, 0, stream>>>(
      (const float*)d_in[0], (const float*)d_in[1], (const float*)d_in[2],
      (const float*)d_in[3], (const float*)d_in[4], (const float*)d_in[5],
      (const float*)d_in[6], (const float*)d_in[7], (const float*)d_in[8],
      (const float*)d_in[9], (const float*)d_in[10], (const float*)d_in[11],
      (const float*)d_in[12], (const float*)d_in[13], (const float*)d_in[14],
      (const float*)d_in[15], (const float*)d_in[16], (float*)d_out);
}

// Round 4
// 127.544 us; speedup vs baseline: 1.0506x; 1.0506x over previous
//
#include <hip/hip_runtime.h>
#include <math.h>

#define L2P 1.8378770664093453f
#define TF 4
#define WUP 8

__device__ __forceinline__ void ld16(float* __restrict__ d, const float* __restrict__ p) {
  const float4 a = *(const float4*)(p);
  const float4 b = *(const float4*)(p + 4);
  const float4 cc = *(const float4*)(p + 8);
  const float4 e = *(const float4*)(p + 12);
  d[0] = a.x; d[1] = a.y; d[2] = a.z; d[3] = a.w;
  d[4] = b.x; d[5] = b.y; d[6] = b.z; d[7] = b.w;
  d[8] = cc.x; d[9] = cc.y; d[10] = cc.z; d[11] = cc.w;
  d[12] = e.x; d[13] = e.y; d[14] = e.z; d[15] = e.w;
}

__device__ __forceinline__ float dot16rr(const float* __restrict__ a,
                                         const float* __restrict__ b) {
  float s0 = 0.f, s1 = 0.f;
#pragma unroll
  for (int k = 0; k < 16; k += 2) {
    s0 = fmaf(a[k], b[k], s0);
    s1 = fmaf(a[k + 1], b[k + 1], s1);
  }
  return s0 + s1;
}

__device__ __forceinline__ float dotshfl16(const float* __restrict__ a, float v) {
  float s0 = 0.f, s1 = 0.f;
#pragma unroll
  for (int k = 0; k < 16; k += 2) {
    s0 = fmaf(a[k], __shfl(v, k, 16), s0);
    s1 = fmaf(a[k + 1], __shfl(v, k + 1, 16), s1);
  }
  return s0 + s1;
}

// 8-pivot block-GJ phase on a 16x32 augmented system (SPD, no pivoting).
// 256-thread version: each thread updates 2 rows (used inside exact loop).
__device__ __forceinline__ float gj8_phase(const float* __restrict__ X,
                                           float* __restrict__ Y, int k, int tid) {
  const int rr0 = tid >> 5;
  const int ca = tid & 31;
  float p[8][8];
#pragma unroll
  for (int i = 0; i < 8; ++i) {
    const float4 v0 = *(const float4*)&X[(k + i) * 32 + k];
    const float4 v1 = *(const float4*)&X[(k + i) * 32 + k + 4];
    p[i][0] = v0.x; p[i][1] = v0.y; p[i][2] = v0.z; p[i][3] = v0.w;
    p[i][4] = v1.x; p[i][5] = v1.y; p[i][6] = v1.z; p[i][7] = v1.w;
  }
  float rhs[8];
#pragma unroll
  for (int i = 0; i < 8; ++i) rhs[i] = X[(k + i) * 32 + ca];
  float det = 1.f;
#pragma unroll
  for (int i = 0; i < 8; ++i) {
    det *= p[i][i];
    const float ip = __builtin_amdgcn_rcpf(p[i][i]);
#pragma unroll
    for (int j = i + 1; j < 8; ++j) p[i][j] *= ip;
    rhs[i] *= ip;
#pragma unroll
    for (int m2 = i + 1; m2 < 8; ++m2) {
      const float f = p[m2][i];
#pragma unroll
      for (int j = i + 1; j < 8; ++j) p[m2][j] = fmaf(-f, p[i][j], p[m2][j]);
      rhs[m2] = fmaf(-f, rhs[i], rhs[m2]);
    }
  }
  float w[8];
#pragma unroll
  for (int i = 7; i >= 0; --i) {
    float s = rhs[i];
#pragma unroll
    for (int j = i + 1; j < 8; ++j) s = fmaf(-p[i][j], w[j], s);
    w[i] = s;
  }
#pragma unroll
  for (int h = 0; h < 2; ++h) {
    const int rr = rr0 + 8 * h;
    float o;
    if (rr >= k && rr < k + 8) {
      o = w[rr - k];
    } else {
      const float4 s0 = *(const float4*)&X[rr * 32 + k];
      const float4 s1 = *(const float4*)&X[rr * 32 + k + 4];
      o = X[rr * 32 + ca] -
          (s0.x * w[0] + s0.y * w[1] + s0.z * w[2] + s0.w * w[3] +
           s1.x * w[4] + s1.y * w[5] + s1.z * w[6] + s1.w * w[7]);
    }
    Y[rr * 32 + ca] = o;
  }
  return det;
}

// Wave-local GJ phase: ONE wave handles the whole 16x32 system, 8 rows/lane.
__device__ __forceinline__ float gjw_phase(const float* __restrict__ X,
                                           float* __restrict__ Y, int k, int lane) {
  const int ca = lane & 31;
  const int r8 = (lane >> 5) * 8;
  float p[8][8];
#pragma unroll
  for (int i = 0; i < 8; ++i) {
    const float4 v0 = *(const float4*)&X[(k + i) * 32 + k];
    const float4 v1 = *(const float4*)&X[(k + i) * 32 + k + 4];
    p[i][0] = v0.x; p[i][1] = v0.y; p[i][2] = v0.z; p[i][3] = v0.w;
    p[i][4] = v1.x; p[i][5] = v1.y; p[i][6] = v1.z; p[i][7] = v1.w;
  }
  float rhs[8];
#pragma unroll
  for (int i = 0; i < 8; ++i) rhs[i] = X[(k + i) * 32 + ca];
  float det = 1.f;
#pragma unroll
  for (int i = 0; i < 8; ++i) {
    det *= p[i][i];
    const float ip = __builtin_amdgcn_rcpf(p[i][i]);
#pragma unroll
    for (int j = i + 1; j < 8; ++j) p[i][j] *= ip;
    rhs[i] *= ip;
#pragma unroll
    for (int m2 = i + 1; m2 < 8; ++m2) {
      const float f = p[m2][i];
#pragma unroll
      for (int j = i + 1; j < 8; ++j) p[m2][j] = fmaf(-f, p[i][j], p[m2][j]);
      rhs[m2] = fmaf(-f, rhs[i], rhs[m2]);
    }
  }
  float w[8];
#pragma unroll
  for (int i = 7; i >= 0; --i) {
    float s = rhs[i];
#pragma unroll
    for (int j = i + 1; j < 8; ++j) s = fmaf(-p[i][j], w[j], s);
    w[i] = s;
  }
#pragma unroll
  for (int h = 0; h < 8; ++h) {
    const int rr = r8 + h;
    float o;
    if (rr >= k && rr < k + 8) {
      o = w[rr - k];
    } else {
      const float4 s0 = *(const float4*)&X[rr * 32 + k];
      const float4 s1 = *(const float4*)&X[rr * 32 + k + 4];
      o = X[rr * 32 + ca] -
          (s0.x * w[0] + s0.y * w[1] + s0.z * w[2] + s0.w * w[3] +
           s1.x * w[4] + s1.y * w[5] + s1.z * w[6] + s1.w * w[7]);
    }
    Y[rr * 32 + ca] = o;
  }
  return det;
}

// Second GJ phase (k=8) storing ONLY the inverse half, scaled, r-major.
__device__ __forceinline__ float gjw_store(const float* __restrict__ X,
                                           float* __restrict__ dst, float scale,
                                           int lane) {
  const int ca = lane & 31;
  const int r8 = (lane >> 5) * 8;
  float p[8][8];
#pragma unroll
  for (int i = 0; i < 8; ++i) {
    const float4 v0 = *(const float4*)&X[(8 + i) * 32 + 8];
    const float4 v1 = *(const float4*)&X[(8 + i) * 32 + 12];
    p[i][0] = v0.x; p[i][1] = v0.y; p[i][2] = v0.z; p[i][3] = v0.w;
    p[i][4] = v1.x; p[i][5] = v1.y; p[i][6] = v1.z; p[i][7] = v1.w;
  }
  float rhs[8];
#pragma unroll
  for (int i = 0; i < 8; ++i) rhs[i] = X[(8 + i) * 32 + ca];
  float det = 1.f;
#pragma unroll
  for (int i = 0; i < 8; ++i) {
    det *= p[i][i];
    const float ip = __builtin_amdgcn_rcpf(p[i][i]);
#pragma unroll
    for (int j = i + 1; j < 8; ++j) p[i][j] *= ip;
    rhs[i] *= ip;
#pragma unroll
    for (int m2 = i + 1; m2 < 8; ++m2) {
      const float f = p[m2][i];
#pragma unroll
      for (int j = i + 1; j < 8; ++j) p[m2][j] = fmaf(-f, p[i][j], p[m2][j]);
      rhs[m2] = fmaf(-f, rhs[i], rhs[m2]);
    }
  }
  float w[8];
#pragma unroll
  for (int i = 7; i >= 0; --i) {
    float s = rhs[i];
#pragma unroll
    for (int j = i + 1; j < 8; ++j) s = fmaf(-p[i][j], w[j], s);
    w[i] = s;
  }
  const bool st = (ca >= 16);
  const int cd = ca - 16;
#pragma unroll
  for (int h = 0; h < 8; ++h) {
    const int rr = r8 + h;
    float o;
    if (rr >= 8) {
      o = w[rr - 8];
    } else {
      const float4 s0 = *(const float4*)&X[rr * 32 + 8];
      const float4 s1 = *(const float4*)&X[rr * 32 + 12];
      o = X[rr * 32 + ca] -
          (s0.x * w[0] + s0.y * w[1] + s0.z * w[2] + s0.w * w[3] +
           s1.x * w[4] + s1.y * w[5] + s1.z * w[6] + s1.w * w[7]);
    }
    if (st) dst[rr * 16 + cd] = scale * o;
  }
  return det;
}

extern "C" __global__ __launch_bounds__(512, 1) void lgq_kernel(
    const float* __restrict__ g_obs, const float* __restrict__ g_ppm,
    const float* __restrict__ g_ppc, const float* __restrict__ g_ptw,
    const float* __restrict__ g_ptb, const float* __restrict__ g_ptc,
    const float* __restrict__ g_pew, const float* __restrict__ g_peb,
    const float* __restrict__ g_pec, const float* __restrict__ g_qpm,
    const float* __restrict__ g_qpc, const float* __restrict__ g_qtw,
    const float* __restrict__ g_qtb, const float* __restrict__ g_qtc,
    const float* __restrict__ g_qew, const float* __restrict__ g_qeb,
    const float* __restrict__ g_qec, float* __restrict__ out) {
  const int tid = threadIdx.x;
  const bool lo = tid < 256;
  const int t8 = tid & 255;
  const int r = t8 >> 4, c = tid & 15;
  const int hf = tid >> 8;
  const int wv = tid >> 6;
  const int lane = tid & 63;

  __shared__ __align__(16) float obs_s[4096];  // reused as w_t after exact loop
  __shared__ __align__(16) float hyb[4096];    // aliased as aug6A in preamble
  __shared__ __align__(16) float eoy[4096];    // aliased as aug6B; becomes eu
  __shared__ float qOmO[256];
  __shared__ float ring[32];
  __shared__ __align__(16) float augA[512], augB[512];
  __shared__ __align__(16) float fcInv[256];
  __shared__ __align__(16) float Wq[256], Hq[256], Wp[256], We[256];
  __shared__ __align__(16) float qtp[256], Rinv[256], Qp0i[256];
  __shared__ __align__(16) float ct[256], M0[256], Eq[256], Eo[256], c3m[256];
  __shared__ __align__(16) float OmT[256], OmO[256], Om0[256];
  __shared__ __align__(16) float F0[256], W2n[256], Tt[256];
  __shared__ __align__(16) float S0[256], S1[256];
  __shared__ __align__(16) float bAT[320], t1T[320], Emat[256], fprec[256];
  __shared__ __align__(16) float bcovS[256], bAfN[256], A0fN[256], A0fT[320];
  __shared__ __align__(16) float ctT[320], WeT[320], Dm[256];
  __shared__ __align__(16) float R1m[256], R1T[320], R2m[256], R2T[320];
  __shared__ __align__(16) float T1m[256], T2m[256];
  __shared__ __align__(16) float BkA[256], BkAT[320], BkB[256], BkBT[320];
  __shared__ __align__(16) float hA256[256], hB256[256];
  __shared__ __align__(16) float eta[16], ba[16], u_t[16], zv[16];
  __shared__ __align__(16) float gb0[16], gb1[16], fm[16];
  __shared__ __align__(16) float etaF[16], gfin[16];
  __shared__ float qtb[16], dqv[16], ptb[16], peb[16], ppmv[16], qpmv[16];
  __shared__ float v0[16], u0[16], wc_s[16], uc_s[16], vta[16], bau0v[16];
  __shared__ float scl[8];
  __shared__ float cB_s;

  float* aug6A = hyb;
  float* aug6B = eoy;

  // ---- phase 0: loads + 6 wave-parallel inversions with direct store ----
#pragma unroll
  for (int j = 0; j < 8; ++j) obs_s[tid + 512 * j] = g_obs[tid + 512 * j];

  float trace_acc = 0.f, hacc = 0.f;

  if (wv < 6) {
    const float* M = (wv == 0) ? g_ptc : (wv == 1) ? g_pec : (wv == 2) ? g_qtc
                     : (wv == 3) ? g_qec : (wv == 4) ? g_ppc : g_qpc;
    float* A = aug6A + wv * 512;
    float* Bp = aug6B + wv * 512;
    const int ca = lane & 31;
    const int r8 = (lane >> 5) * 8;
#pragma unroll
    for (int h = 0; h < 8; ++h) {
      const int rr = r8 + h;
      A[rr * 32 + ca] = (ca < 16) ? M[rr * 16 + ca] : ((rr == ca - 16) ? 1.f : 0.f);
    }
    const float d0 = gjw_phase(A, Bp, 0, lane);
    float* dst = (wv == 0) ? OmT : (wv == 1) ? OmO : (wv == 2) ? qtp
                 : (wv == 3) ? Rinv : (wv == 4) ? Om0 : Qp0i;
    const float scale = (wv == 2 || wv == 3 || wv == 5) ? 1.0f : -0.5f;
    const float d1 = gjw_store(Bp, dst, scale, lane);
    if (lane == 0) { ring[wv * 2] = d0; ring[wv * 2 + 1] = d1; }
  } else if (wv == 6) {
    if (lane < 16) {
      qtb[lane] = g_qtb[lane];
      dqv[lane] = g_qeb[lane];
      ptb[lane] = g_ptb[lane];
      peb[lane] = g_peb[lane];
    } else if (lane < 32) {
      const int i = lane - 16;
      ppmv[i] = g_ppm[i];
      qpmv[i] = g_qpm[i];
    }
  } else {  // wv == 7
#pragma unroll
    for (int j = 0; j < 4; ++j) {
      const int i = lane + 64 * j;
      Wq[i] = g_qtw[i];
      Hq[i] = g_qew[i];
      Wp[i] = g_ptw[i];
      We[i] = g_pew[i];
    }
  }

  // ---- mmA (512-split): ct,Eq | Tt,Eo ----
  __syncthreads();
  if (!hf) {
    float a = 0.f, b = 0.f;
#pragma unroll
    for (int k = 0; k < 16; ++k) {
      a = fmaf(Wq[k * 16 + r], qtp[k * 16 + c], a);
      b = fmaf(Hq[k * 16 + r], Rinv[k * 16 + c], b);
    }
    ct[t8] = a;
    Eq[t8] = b;
  } else {
    float d = 0.f, e = 0.f;
#pragma unroll
    for (int k = 0; k < 16; ++k) {
      d = fmaf(OmT[r * 16 + k], Wp[k * 16 + c], d);
      e = fmaf(We[k * 16 + r], OmO[k * 16 + c], e);
    }
    Tt[t8] = d;
    Eo[t8] = e;
  }

  // ---- fused: batch per-t vectors + mmBCD (both 512-split) ----
  __syncthreads();
  {
    float ym[16], ob[16];
#pragma unroll
    for (int k = 0; k < 16; ++k) {
      const float y = obs_s[t8 * 16 + k];
      ym[k] = y - dqv[k];
      ob[k] = peb[k] - y;
    }
    const int i0 = hf * 8;
#pragma unroll
    for (int i2 = 0; i2 < 8; ++i2) {
      const int i = i0 + i2;
      float a = 0.f, b = 0.f;
#pragma unroll
      for (int k = 0; k < 16; ++k) {
        a = fmaf(Eq[i * 16 + k], ym[k], a);
        b = fmaf(Eo[i * 16 + k], ob[k], b);
      }
      hyb[t8 * 16 + i] = a;
      eoy[t8 * 16 + i] = b;
    }
    if (hf) {
      float q = 0.f;
#pragma unroll
      for (int i = 0; i < 16; ++i) {
        float d = 0.f;
#pragma unroll
        for (int k = 0; k < 16; ++k) d = fmaf(OmO[i * 16 + k], ob[k], d);
        q = fmaf(ob[i], d, q);
      }
      qOmO[t8] = q;
    }
  }
  if (!hf) {
    float a = 0.f, b = 0.f;
#pragma unroll
    for (int k = 0; k < 16; ++k) {
      a = fmaf(ct[r * 16 + k], Wq[k * 16 + c], a);
      b = fmaf(Eq[r * 16 + k], Hq[k * 16 + c], b);
    }
    M0[t8] = a;
    F0[t8] = qtp[t8] + b;
    fprec[t8] = Qp0i[t8] + b;
    if (tid < 16) {
      float s = 0.f;
#pragma unroll
      for (int k = 0; k < 16; ++k) s = fmaf(ct[tid * 16 + k], qtb[k], s);
      u0[tid] = s;
    } else if (tid < 32) {
      const int i = tid - 16;
      float s = 0.f;
#pragma unroll
      for (int k = 0; k < 16; ++k) s = fmaf(qtp[i * 16 + k], qtb[k], s);
      v0[i] = s;
    } else if (tid < 48) {
      const int i = tid - 32;
      float s = 0.f;
#pragma unroll
      for (int k = 0; k < 16; ++k) s = fmaf(Om0[i * 16 + k], ppmv[k], s);
      vta[i] = s;
    } else if (tid < 64) {
      const int i = tid - 48;
      float s = 0.f;
#pragma unroll
      for (int k = 0; k < 16; ++k) s = fmaf(Tt[k * 16 + i], ptb[k], s);
      wc_s[i] = s;
    } else if (tid < 80) {
      const int i = tid - 64;
      float s = 0.f;
#pragma unroll
      for (int k = 0; k < 16; ++k) s = fmaf(OmT[i * 16 + k], ptb[k], s);
      uc_s[i] = s;
    }
  } else {
    float e = 0.f, co = 0.f;
#pragma unroll
    for (int k = 0; k < 16; ++k) {
      e = fmaf(Wp[k * 16 + r], Tt[k * 16 + c], e);
      co = fmaf(Eo[r * 16 + k], We[k * 16 + c], co);
    }
    W2n[t8] = e;
    S0[t8] = Om0[t8] + co + e;   // Sw_1
    c3m[t8] = OmT[t8] + co + e;  // c3
  }

  // ---- mmE: eta0/gb0/cB/hacc init ; register constants ; fill augA ----
  float ct_c[16], ct_r[16], tt_r[16], wp_r[16];
  float f0_rc, d0_rc, c3_rc;
  __syncthreads();
  if (lo) {
    if (tid < 16) {
      float s = hyb[tid];
#pragma unroll
      for (int k = 0; k < 16; ++k) s = fmaf(Qp0i[tid * 16 + k], qpmv[k], s);
      eta[tid] = s;
      hacc += ppmv[tid] * vta[tid];
    } else if (tid < 32) {
      const int i = tid - 16;
      gb0[i] = eoy[i] - vta[i];
    }
    if (tid == 0) {
      float s = 0.f;
#pragma unroll
      for (int k = 0; k < 16; ++k) s = fmaf(ptb[k], uc_s[k], s);
      cB_s = s;
      hacc += qOmO[0];
    }
#pragma unroll
    for (int k = 0; k < 16; ++k) {
      ct_c[k] = ct[k * 16 + c];
      ct_r[k] = ct[k * 16 + r];
      tt_r[k] = Tt[r * 16 + k];
      wp_r[k] = Wp[r * 16 + k];
    }
    f0_rc = F0[tid];
    d0_rc = M0[tid] + F0[tid];
    c3_rc = c3m[tid];
    augA[r * 32 + c] = M0[tid] + fprec[tid];
    augA[r * 32 + 16 + c] = (r == c) ? 1.f : 0.f;
  }

  float* Scur = S0;
  float* Snxt = S1;
  float* gcur = gb0;
  float* gnxt = gb1;

  // ================= exact forward t = 1..TF : 4 phases/step =============
#pragma unroll 1
  for (int t = 1; t <= TF; ++t) {
    const int rb = 12 + (t - 1) * 2;
    float sw_rc;
    __syncthreads();
    if (lo) {
      const float det = gj8_phase(augA, augB, 0, tid);
      if (tid == 0) ring[rb + 0] = det;
    } else if (wv == 4 && t > 1) {
      // Snxt offload (concurrent with lo's GJ phase)
      const int ec = lane & 15, er0 = lane >> 4;
      float t1c[16]; ld16(t1c, &t1T[ec * 20]);
#pragma unroll
      for (int q = 0; q < 4; ++q) {
        const int er = er0 + 4 * q;
        const int e = er * 16 + ec;
        float btr[16]; ld16(btr, &bAT[er * 20]);
        Snxt[e] = dot16rr(btr, t1c) - Emat[er * 16 + ec] - Emat[ec * 16 + er] + c3m[e];
      }
    } else if (wv == 5 && t > 1) {
      if (lane < 16) {
        float bti[16]; ld16(bti, &bAT[lane * 20]);
        float zvv[16]; ld16(zvv, zv);
        gnxt[lane] = -u_t[lane] + eoy[(t - 1) * 16 + lane] + dot16rr(bti, zvv);
      }
    }
    if (t > 1) {
      float* tp = Scur; Scur = Snxt; Snxt = tp;
      tp = gcur; gcur = gnxt; gnxt = tp;
    }
    __syncthreads();
    if (lo) {
      const float det = gj8_phase(augB, augA, 8, tid);
      if (tid == 0) ring[rb + 1] = det;
    }
    // Q1
    __syncthreads();
    if (lo) {
      float brow[16]; ld16(brow, &augA[r * 32 + 16]);
      const float acc = dot16rr(brow, ct_c);
      bAT[c * 20 + r] = acc;
      const float bce = augA[r * 32 + 16 + c];
      if (t == TF) { bAfN[tid] = acc; bcovS[tid] = bce; }
      sw_rc = Scur[tid];
      trace_acc = fmaf(bce, sw_rc, trace_acc);
      if (tid < 16) {
        float bc[16]; ld16(bc, &augA[tid * 32 + 16]);
        float a2 = 0.f;
#pragma unroll
        for (int k = 0; k < 16; ++k) a2 = fmaf(bc[k], eta[k] - u0[k], a2);
        ba[tid] = a2;
      }
    }
    // Q2
    __syncthreads();
    if (lo) {
      float bcol[16]; ld16(bcol, &bAT[c * 20]);
      float swr[16];  ld16(swr, &Scur[r * 16]);
      float a1 = 0.f, ae = 0.f, af = 0.f;
#pragma unroll
      for (int k = 0; k < 16; ++k) {
        a1 = fmaf(swr[k], bcol[k], a1);
        ae = fmaf(tt_r[k], bcol[k], ae);
        af = fmaf(ct_r[k], bcol[k], af);
      }
      t1T[c * 20 + r] = a1;
      Emat[tid] = ae;
      fprec[tid] = f0_rc - af;
      augA[r * 32 + c] = d0_rc - af;
      augA[r * 32 + 16 + c] = (r == c) ? 1.f : 0.f;
      if (t == TF) {
        float a0 = 0.f;
#pragma unroll
        for (int k = 0; k < 16; ++k) a0 = fmaf(wp_r[k], bcol[k], a0);
        a0 -= (r == c) ? 1.f : 0.f;
        A0fN[tid] = a0;
        A0fT[c * 20 + r] = a0;
      }
      const float bar = ba[r], bac = ba[c];
      hacc = fmaf(bar * sw_rc, bac, hacc);
      if (r == 0) hacc += 2.f * bac * (gcur[c] + wc_s[c]);
      if (tid == 0) hacc += cB_s + qOmO[t];
    } else if (wv == 5) {
      // eta / u_t / zv offload (concurrent with lo's Q2)
      if (lane < 16) {
        const int i = lane;
        float e = v0[i] + hyb[t * 16 + i];
#pragma unroll
        for (int k = 0; k < 16; ++k) e = fmaf(ct[k * 16 + i], ba[k], e);
        eta[i] = e;
      } else if (lane < 32) {
        const int i = lane - 16;
        float ttrow[16]; ld16(ttrow, &Tt[i * 16]);
        float bav[16]; ld16(bav, ba);
        u_t[i] = uc_s[i] + dot16rr(ttrow, bav);
      } else if (lane < 48) {
        const int i = lane - 32;
        float swrow[16]; ld16(swrow, &Scur[i * 16]);
        float bav[16]; ld16(bav, ba);
        zv[i] = gcur[i] + wc_s[i] + dot16rr(swrow, bav);
      }
    } else if (wv == 6 && t == TF) {
      // bau0v offload (bcovS written in Q1, barrier-ordered)
      if (lane < 16) {
        float bc[16]; ld16(bc, &bcovS[lane * 16]);
        float u0v[16]; ld16(u0v, u0);
        bau0v[lane] = dot16rr(bc, u0v);
      }
    }
  }

  // ---- fused: transition (lo) + w/eu batch (hi 256, 16 outputs each) ----
  __syncthreads();
  if (lo) {
    float btr[16]; ld16(btr, &bAT[r * 20]);
    float t1c[16]; ld16(t1c, &t1T[c * 20]);
    Snxt[tid] = dot16rr(btr, t1c) - Emat[r * 16 + c] - Emat[c * 16 + r] + c3_rc;
    float bcr[16]; ld16(bcr, &bcovS[r * 16]);
    float ctrow[16]; ld16(ctrow, &ct[c * 16]);
    Dm[tid] = dot16rr(bcr, ctrow);  // D[r][c] = sum_k bcov[r][k] ct[c][k]
    ctT[c * 20 + r] = ct[tid];
    WeT[c * 20 + r] = We[tid];
  } else {
    float tmp[16];
#pragma unroll
    for (int k = 0; k < 16; ++k) tmp[k] = v0[k] + hyb[t8 * 16 + k];
#pragma unroll
    for (int i = 0; i < 16; ++i) {
      float s = -bau0v[i];
#pragma unroll
      for (int k = 0; k < 16; ++k) s = fmaf(bcovS[i * 16 + k], tmp[k], s);
      obs_s[t8 * 16 + i] = s;
    }
    if (t8 >= TF) {
#pragma unroll
      for (int i = 0; i < 16; ++i) eoy[t8 * 16 + i] -= uc_s[i];
    }
  }
  { float* tp = Scur; Scur = Snxt; Snxt = tp; }

  // ======= waves 0-3: steady-state chain t=TF+1..255 (16 chunks)
  // ======= wave 4: final fc inversion ; wave 5: S1 + Lyapunov (concurrent)
  __syncthreads();
  if (lo) {
    const int grp = tid >> 4;
    const int i = tid & 15;
    float drow[16], swr[16], ttr[16], bcol[16];
    ld16(drow, &Dm[i * 16]);   // D row i
    ld16(swr, &Scur[i * 16]);  // Sw* row i
    ld16(ttr, &Tt[i * 16]);    // Tt row i
    ld16(bcol, &bAT[i * 20]);  // B col i
    const float wci = wc_s[i];
    float ba_p, zv_p;
    if (grp == 0) {
      ba_p = ba[i]; zv_p = zv[i];
    } else {
      ba_p = 0.f; zv_p = 0.f;
    }
    float haccA = 0.f, haccB = 0.f;
    const int tstart = (TF + 1) + grp * 16 - WUP;
#pragma unroll 1
    for (int j = 0; j < WUP + 16; ++j) {
      if (grp == 0 && j < WUP) continue;
      const int t = tstart + j;
      const int trd = (t > 255) ? 255 : t;
      const float w_c = obs_s[(trd - 1) * 16 + i];
      const float eu_c = eoy[(trd - 1) * 16 + i];
      const float ban = dotshfl16(drow, ba_p) + w_c;
      const float q = dotshfl16(ttr, ba_p);
      const float bz = dotshfl16(bcol, zv_p);
      const float gnew = eu_c - q + bz;
      const float ssw = dotshfl16(swr, ban);
      if (j >= WUP && t <= 255) {
        haccA = fmaf(ban, ssw, haccA);
        haccB = fmaf(ban, gnew + wci, haccB);
      }
      if (t <= 255) {
        zv_p = gnew + wci + ssw;
        ba_p = ban;
      }
    }
    hA256[tid] = haccA;
    hB256[tid] = haccB;
    if (grp == 15) {
      // tail: g_256 = eu_255 - Tt ba_255 + B^T zv_255 ; eta_256
      const float eu_c = eoy[255 * 16 + i];
      gfin[i] = eu_c - dotshfl16(ttr, ba_p) + dotshfl16(bcol, zv_p);
      float ctcol[16]; ld16(ctcol, &ctT[i * 20]);
      etaF[i] = v0[i] + hyb[255 * 16 + i] + dotshfl16(ctcol, ba_p);
    }
  } else if (wv == 4) {
    // final fc = inv(fprec*): wave-local, 2 GJ phases, direct store
    const int ca = lane & 31;
    const int r8 = (lane >> 5) * 8;
#pragma unroll
    for (int h = 0; h < 8; ++h) {
      const int rr = r8 + h;
      augA[rr * 32 + ca] = (ca < 16) ? fprec[rr * 16 + ca] : ((rr == ca - 16) ? 1.f : 0.f);
    }
    const float d0 = gjw_phase(augA, augB, 0, lane);
    const float d1 = gjw_store(augB, fcInv, 1.0f, lane);
    if (lane == 0) { ring[12 + TF * 2] = d0; ring[12 + TF * 2 + 1] = d1; }
  } else if (wv == 5) {
    // S1 (R inits, Bk init) + 4x Lyapunov doubling, wave-local
    const int ec = lane & 15, er0 = lane >> 4;
    {
      float a0c[16]; ld16(a0c, &A0fT[ec * 20]);
      float wec[16]; ld16(wec, &WeT[ec * 20]);
#pragma unroll
      for (int q = 0; q < 4; ++q) {
        const int er = er0 + 4 * q;
        const int e = er * 16 + ec;
        float omtr[16]; ld16(omtr, &OmT[er * 16]);
        float omor[16]; ld16(omor, &OmO[er * 16]);
        const float c1 = dot16rr(omtr, a0c);
        R1m[e] = c1; R1T[ec * 20 + er] = c1;
        const float c2 = dot16rr(omor, wec);
        R2m[e] = c2; R2T[ec * 20 + er] = c2;
        BkA[e] = bAfN[e];
        BkAT[ec * 20 + er] = bAT[ec * 20 + er];
      }
    }
    float* pBk = BkA;  float* pBkT = BkAT;
    float* pBn = BkB;  float* pBnT = BkBT;
#pragma unroll 1
    for (int it = 0; it < 4; ++it) {
      {
        float r1c[16]; ld16(r1c, &R1T[ec * 20]);
        float r2c[16]; ld16(r2c, &R2T[ec * 20]);
        float bkc[16]; ld16(bkc, &pBkT[ec * 20]);
#pragma unroll
        for (int q = 0; q < 4; ++q) {
          const int er = er0 + 4 * q;
          const int e = er * 16 + ec;
          float bkr[16]; ld16(bkr, &pBk[er * 16]);
          T1m[e] = dot16rr(bkr, r1c);
          T2m[e] = dot16rr(bkr, r2c);
          const float bsq = dot16rr(bkr, bkc);
          pBn[e] = bsq;
          pBnT[ec * 20 + er] = bsq;
        }
      }
      {
        float bkc[16]; ld16(bkc, &pBkT[ec * 20]);
#pragma unroll
        for (int q = 0; q < 4; ++q) {
          const int er = er0 + 4 * q;
          const int e = er * 16 + ec;
          float t1r[16]; ld16(t1r, &T1m[er * 16]);
          float t2r[16]; ld16(t2r, &T2m[er * 16]);
          const float n1 = R1m[e] + dot16rr(t1r, bkc);
          const float n2 = R2m[e] + dot16rr(t2r, bkc);
          R1m[e] = n1; R1T[ec * 20 + er] = n1;
          R2m[e] = n2; R2T[ec * 20 + er] = n2;
        }
      }
      { float* tp = pBk; pBk = pBn; pBn = tp; }
      { float* tp = pBkT; pBkT = pBnT; pBnT = tp; }
    }
  }

  // ---- join: fm = fc * etaF ----
  __syncthreads();
  if (tid < 16) {
    float fr[16]; ld16(fr, &fcInv[tid * 16]);
    float ev[16]; ld16(ev, etaF);
    fm[tid] = dot16rr(fr, ev);
  }
  __syncthreads();

  // ---- final reduce & output (Z folded in) ----
  {
    float psum = 0.f;
    if (lo) {
      const float cnt = 255.f - (float)TF;
      psum = trace_acc + hacc;
      psum += cnt * bcovS[tid] * Scur[tid];
      {
        float a0rowc[16]; ld16(a0rowc, &A0fN[c * 16]);
        float r1colr[16]; ld16(r1colr, &R1T[r * 20]);
        float werowc[16]; ld16(werowc, &We[c * 16]);
        float r2colr[16]; ld16(r2colr, &R2T[r * 20]);
        const float zcr = dot16rr(a0rowc, r1colr) + dot16rr(werowc, r2colr);
        psum += fcInv[tid] * zcr;
      }
      psum += fm[r] * (Scur[tid] - W2n[tid]) * fm[c];
      if (r == 0) psum += 2.f * fm[c] * gfin[c];
      psum += hA256[tid] + 2.f * hB256[tid];
      if (tid > TF) psum += qOmO[tid];
      if (tid == 0) psum += cnt * cB_s;
#pragma unroll 1
      for (int i = tid; i < 12 + TF * 2 + 2; i += 256) {
        float w;
        if (i < 2) w = 255.f;
        else if (i < 4) w = 256.f;
        else if (i < 8) w = 0.f;
        else if (i < 10) w = 1.f;
        else if (i < 12) w = 0.f;
        else if (i < 12 + TF * 2) w = (i >= 12 + (TF - 1) * 2) ? (1.f + cnt) : 1.f;
        else w = 1.f;
        if (w != 0.f) psum -= 0.5f * w * logf(ring[i]);
      }
    }
#pragma unroll
    for (int off = 32; off; off >>= 1) psum += __shfl_down(psum, off, 64);
    if ((tid & 63) == 0) scl[tid >> 6] = psum;
  }
  __syncthreads();
  if (tid == 0) {
    const float base = -16.f * L2P + 255.f * (8.f - 8.f * L2P) + 8.f * L2P + 8.f;
    out[0] = scl[0] + scl[1] + scl[2] + scl[3] + scl[4] + scl[5] + scl[6] + scl[7] + base;
  }
}

extern "C" void kernel_launch(void* const* d_in, const int* in_sizes, int n_in,
                              void* d_out, int out_size, void* d_ws, size_t ws_size,
                              hipStream_t stream) {
  (void)in_sizes; (void)n_in; (void)out_size; (void)d_ws; (void)ws_size;
  lgq_kernel<<<1, 512, 0, stream>>>(
      (const float*)d_in[0], (const float*)d_in[1], (const float*)d_in[2],
      (const float*)d_in[3], (const float*)d_in[4], (const float*)d_in[5],
      (const float*)d_in[6], (const float*)d_in[7], (const float*)d_in[8],
      (const float*)d_in[9], (const float*)d_in[10], (const float*)d_in[11],
      (const float*)d_in[12], (const float*)d_in[13], (const float*)d_in[14],
      (const float*)d_in[15], (const float*)d_in[16], (float*)d_out);
}

// Round 5
// 121.751 us; speedup vs baseline: 1.1006x; 1.0476x over previous
//
#include <hip/hip_runtime.h>
#include <math.h>

#define L2P 1.8378770664093453f
#define TF 4
#define WUP 8

__device__ __forceinline__ void ld16(float* __restrict__ d, const float* __restrict__ p) {
  const float4 a = *(const float4*)(p);
  const float4 b = *(const float4*)(p + 4);
  const float4 cc = *(const float4*)(p + 8);
  const float4 e = *(const float4*)(p + 12);
  d[0] = a.x; d[1] = a.y; d[2] = a.z; d[3] = a.w;
  d[4] = b.x; d[5] = b.y; d[6] = b.z; d[7] = b.w;
  d[8] = cc.x; d[9] = cc.y; d[10] = cc.z; d[11] = cc.w;
  d[12] = e.x; d[13] = e.y; d[14] = e.z; d[15] = e.w;
}

__device__ __forceinline__ float dot16rr(const float* __restrict__ a,
                                         const float* __restrict__ b) {
  float s0 = 0.f, s1 = 0.f;
#pragma unroll
  for (int k = 0; k < 16; k += 2) {
    s0 = fmaf(a[k], b[k], s0);
    s1 = fmaf(a[k + 1], b[k + 1], s1);
  }
  return s0 + s1;
}

__device__ __forceinline__ float dotshfl16(const float* __restrict__ a, float v) {
  float s0 = 0.f, s1 = 0.f;
#pragma unroll
  for (int k = 0; k < 16; k += 2) {
    s0 = fmaf(a[k], __shfl(v, k, 16), s0);
    s1 = fmaf(a[k + 1], __shfl(v, k + 1, 16), s1);
  }
  return s0 + s1;
}

// 8-pivot block-GJ phase on a 16x32 augmented system (SPD, no pivoting).
// 256-thread version: each thread updates 2 rows (used inside exact loop).
__device__ __forceinline__ float gj8_phase(const float* __restrict__ X,
                                           float* __restrict__ Y, int k, int tid) {
  const int rr0 = tid >> 5;
  const int ca = tid & 31;
  float p[8][8];
#pragma unroll
  for (int i = 0; i < 8; ++i) {
    const float4 v0 = *(const float4*)&X[(k + i) * 32 + k];
    const float4 v1 = *(const float4*)&X[(k + i) * 32 + k + 4];
    p[i][0] = v0.x; p[i][1] = v0.y; p[i][2] = v0.z; p[i][3] = v0.w;
    p[i][4] = v1.x; p[i][5] = v1.y; p[i][6] = v1.z; p[i][7] = v1.w;
  }
  float rhs[8];
#pragma unroll
  for (int i = 0; i < 8; ++i) rhs[i] = X[(k + i) * 32 + ca];
  float det = 1.f;
#pragma unroll
  for (int i = 0; i < 8; ++i) {
    det *= p[i][i];
    const float ip = __builtin_amdgcn_rcpf(p[i][i]);
#pragma unroll
    for (int j = i + 1; j < 8; ++j) p[i][j] *= ip;
    rhs[i] *= ip;
#pragma unroll
    for (int m2 = i + 1; m2 < 8; ++m2) {
      const float f = p[m2][i];
#pragma unroll
      for (int j = i + 1; j < 8; ++j) p[m2][j] = fmaf(-f, p[i][j], p[m2][j]);
      rhs[m2] = fmaf(-f, rhs[i], rhs[m2]);
    }
  }
  float w[8];
#pragma unroll
  for (int i = 7; i >= 0; --i) {
    float s = rhs[i];
#pragma unroll
    for (int j = i + 1; j < 8; ++j) s = fmaf(-p[i][j], w[j], s);
    w[i] = s;
  }
#pragma unroll
  for (int h = 0; h < 2; ++h) {
    const int rr = rr0 + 8 * h;
    float o;
    if (rr >= k && rr < k + 8) {
      o = w[rr - k];
    } else {
      const float4 s0 = *(const float4*)&X[rr * 32 + k];
      const float4 s1 = *(const float4*)&X[rr * 32 + k + 4];
      o = X[rr * 32 + ca] -
          (s0.x * w[0] + s0.y * w[1] + s0.z * w[2] + s0.w * w[3] +
           s1.x * w[4] + s1.y * w[5] + s1.z * w[6] + s1.w * w[7]);
    }
    Y[rr * 32 + ca] = o;
  }
  return det;
}

// Wave-local GJ phase: ONE wave handles the whole 16x32 system, 8 rows/lane.
__device__ __forceinline__ float gjw_phase(const float* __restrict__ X,
                                           float* __restrict__ Y, int k, int lane) {
  const int ca = lane & 31;
  const int r8 = (lane >> 5) * 8;
  float p[8][8];
#pragma unroll
  for (int i = 0; i < 8; ++i) {
    const float4 v0 = *(const float4*)&X[(k + i) * 32 + k];
    const float4 v1 = *(const float4*)&X[(k + i) * 32 + k + 4];
    p[i][0] = v0.x; p[i][1] = v0.y; p[i][2] = v0.z; p[i][3] = v0.w;
    p[i][4] = v1.x; p[i][5] = v1.y; p[i][6] = v1.z; p[i][7] = v1.w;
  }
  float rhs[8];
#pragma unroll
  for (int i = 0; i < 8; ++i) rhs[i] = X[(k + i) * 32 + ca];
  float det = 1.f;
#pragma unroll
  for (int i = 0; i < 8; ++i) {
    det *= p[i][i];
    const float ip = __builtin_amdgcn_rcpf(p[i][i]);
#pragma unroll
    for (int j = i + 1; j < 8; ++j) p[i][j] *= ip;
    rhs[i] *= ip;
#pragma unroll
    for (int m2 = i + 1; m2 < 8; ++m2) {
      const float f = p[m2][i];
#pragma unroll
      for (int j = i + 1; j < 8; ++j) p[m2][j] = fmaf(-f, p[i][j], p[m2][j]);
      rhs[m2] = fmaf(-f, rhs[i], rhs[m2]);
    }
  }
  float w[8];
#pragma unroll
  for (int i = 7; i >= 0; --i) {
    float s = rhs[i];
#pragma unroll
    for (int j = i + 1; j < 8; ++j) s = fmaf(-p[i][j], w[j], s);
    w[i] = s;
  }
#pragma unroll
  for (int h = 0; h < 8; ++h) {
    const int rr = r8 + h;
    float o;
    if (rr >= k && rr < k + 8) {
      o = w[rr - k];
    } else {
      const float4 s0 = *(const float4*)&X[rr * 32 + k];
      const float4 s1 = *(const float4*)&X[rr * 32 + k + 4];
      o = X[rr * 32 + ca] -
          (s0.x * w[0] + s0.y * w[1] + s0.z * w[2] + s0.w * w[3] +
           s1.x * w[4] + s1.y * w[5] + s1.z * w[6] + s1.w * w[7]);
    }
    Y[rr * 32 + ca] = o;
  }
  return det;
}

// Second GJ phase (k=8) storing ONLY the inverse half, scaled, r-major.
__device__ __forceinline__ float gjw_store(const float* __restrict__ X,
                                           float* __restrict__ dst, float scale,
                                           int lane) {
  const int ca = lane & 31;
  const int r8 = (lane >> 5) * 8;
  float p[8][8];
#pragma unroll
  for (int i = 0; i < 8; ++i) {
    const float4 v0 = *(const float4*)&X[(8 + i) * 32 + 8];
    const float4 v1 = *(const float4*)&X[(8 + i) * 32 + 12];
    p[i][0] = v0.x; p[i][1] = v0.y; p[i][2] = v0.z; p[i][3] = v0.w;
    p[i][4] = v1.x; p[i][5] = v1.y; p[i][6] = v1.z; p[i][7] = v1.w;
  }
  float rhs[8];
#pragma unroll
  for (int i = 0; i < 8; ++i) rhs[i] = X[(8 + i) * 32 + ca];
  float det = 1.f;
#pragma unroll
  for (int i = 0; i < 8; ++i) {
    det *= p[i][i];
    const float ip = __builtin_amdgcn_rcpf(p[i][i]);
#pragma unroll
    for (int j = i + 1; j < 8; ++j) p[i][j] *= ip;
    rhs[i] *= ip;
#pragma unroll
    for (int m2 = i + 1; m2 < 8; ++m2) {
      const float f = p[m2][i];
#pragma unroll
      for (int j = i + 1; j < 8; ++j) p[m2][j] = fmaf(-f, p[i][j], p[m2][j]);
      rhs[m2] = fmaf(-f, rhs[i], rhs[m2]);
    }
  }
  float w[8];
#pragma unroll
  for (int i = 7; i >= 0; --i) {
    float s = rhs[i];
#pragma unroll
    for (int j = i + 1; j < 8; ++j) s = fmaf(-p[i][j], w[j], s);
    w[i] = s;
  }
  const bool st = (ca >= 16);
  const int cd = ca - 16;
#pragma unroll
  for (int h = 0; h < 8; ++h) {
    const int rr = r8 + h;
    float o;
    if (rr >= 8) {
      o = w[rr - 8];
    } else {
      const float4 s0 = *(const float4*)&X[rr * 32 + 8];
      const float4 s1 = *(const float4*)&X[rr * 32 + 12];
      o = X[rr * 32 + ca] -
          (s0.x * w[0] + s0.y * w[1] + s0.z * w[2] + s0.w * w[3] +
           s1.x * w[4] + s1.y * w[5] + s1.z * w[6] + s1.w * w[7]);
    }
    if (st) dst[rr * 16 + cd] = scale * o;
  }
  return det;
}

extern "C" __global__ __launch_bounds__(512, 1) void lgq_kernel(
    const float* __restrict__ g_obs, const float* __restrict__ g_ppm,
    const float* __restrict__ g_ppc, const float* __restrict__ g_ptw,
    const float* __restrict__ g_ptb, const float* __restrict__ g_ptc,
    const float* __restrict__ g_pew, const float* __restrict__ g_peb,
    const float* __restrict__ g_pec, const float* __restrict__ g_qpm,
    const float* __restrict__ g_qpc, const float* __restrict__ g_qtw,
    const float* __restrict__ g_qtb, const float* __restrict__ g_qtc,
    const float* __restrict__ g_qew, const float* __restrict__ g_qeb,
    const float* __restrict__ g_qec, float* __restrict__ out) {
  const int tid = threadIdx.x;
  const bool lo = tid < 256;
  const int t8 = tid & 255;
  const int r = t8 >> 4, c = tid & 15;
  const int hf = tid >> 8;
  const int wv = tid >> 6;
  const int lane = tid & 63;

  __shared__ __align__(16) float obs_s[4096];  // reused as w_t after exact loop
  __shared__ __align__(16) float hyb[4096];    // aliased as aug6A in preamble
  __shared__ __align__(16) float eoy[4096];    // aliased as aug6B; becomes eu
  __shared__ float qOmO[256];
  __shared__ float ring[32];
  __shared__ __align__(16) float augA[512], augB[512];
  __shared__ __align__(16) float fcInv[256];
  __shared__ __align__(16) float Wq[256], Hq[256], Wp[256], We[256];
  __shared__ __align__(16) float qtp[256], Rinv[256], Qp0i[256];
  __shared__ __align__(16) float ct[256], Eq[256], Eo[256], c3m[256];
  __shared__ __align__(16) float OmT[256], OmO[256], Om0[256];
  __shared__ __align__(16) float W2n[256], Tt[256];
  __shared__ __align__(16) float S0[256], S1[256];
  __shared__ __align__(16) float bAT[320], t1T[320], Emat[256], fprec[256];
  __shared__ __align__(16) float bcovS[256], bAfN[256], A0fN[256], A0fT[320];
  __shared__ __align__(16) float ctT[320], WeT[320], Dm[256];
  __shared__ __align__(16) float R1m[256], R1T[320], R2m[256], R2T[320];
  __shared__ __align__(16) float T1m[256], T2m[256];
  __shared__ __align__(16) float BkA[256], BkAT[320], BkB[256], BkBT[320];
  __shared__ __align__(16) float hA256[256], hB256[256];
  __shared__ __align__(16) float eta[16], ba[16], u_t[16], zv[16];
  __shared__ __align__(16) float gb0[16], gb1[16];
  __shared__ __align__(16) float etaF[16], gfin[16];
  __shared__ float qtb[16], dqv[16], ptb[16], peb[16], ppmv[16], qpmv[16];
  __shared__ float v0[16], u0[16], wc_s[16], uc_s[16], vta[16], bau0v[16];
  __shared__ float scl[8];
  __shared__ float cB_s;

  float* aug6A = hyb;
  float* aug6B = eoy;

  // ---- phase 0: loads + 6 wave-parallel inversions with direct store ----
#pragma unroll
  for (int j = 0; j < 8; ++j) obs_s[tid + 512 * j] = g_obs[tid + 512 * j];

  float trace_acc = 0.f, hacc = 0.f;

  if (wv < 6) {
    const float* M = (wv == 0) ? g_ptc : (wv == 1) ? g_pec : (wv == 2) ? g_qtc
                     : (wv == 3) ? g_qec : (wv == 4) ? g_ppc : g_qpc;
    float* A = aug6A + wv * 512;
    float* Bp = aug6B + wv * 512;
    const int ca = lane & 31;
    const int r8 = (lane >> 5) * 8;
#pragma unroll
    for (int h = 0; h < 8; ++h) {
      const int rr = r8 + h;
      A[rr * 32 + ca] = (ca < 16) ? M[rr * 16 + ca] : ((rr == ca - 16) ? 1.f : 0.f);
    }
    const float d0 = gjw_phase(A, Bp, 0, lane);
    float* dst = (wv == 0) ? OmT : (wv == 1) ? OmO : (wv == 2) ? qtp
                 : (wv == 3) ? Rinv : (wv == 4) ? Om0 : Qp0i;
    const float scale = (wv == 2 || wv == 3 || wv == 5) ? 1.0f : -0.5f;
    const float d1 = gjw_store(Bp, dst, scale, lane);
    if (lane == 0) { ring[wv * 2] = d0; ring[wv * 2 + 1] = d1; }
  } else if (wv == 6) {
    if (lane < 16) {
      qtb[lane] = g_qtb[lane];
      dqv[lane] = g_qeb[lane];
      ptb[lane] = g_ptb[lane];
      peb[lane] = g_peb[lane];
    } else if (lane < 32) {
      const int i = lane - 16;
      ppmv[i] = g_ppm[i];
      qpmv[i] = g_qpm[i];
    }
  } else {  // wv == 7
#pragma unroll
    for (int j = 0; j < 4; ++j) {
      const int i = lane + 64 * j;
      Wq[i] = g_qtw[i];
      Hq[i] = g_qew[i];
      Wp[i] = g_ptw[i];
      We[i] = g_pew[i];
    }
  }

  // ---- mmA (512-split): ct,Eq | Tt,Eo ----
  __syncthreads();
  if (!hf) {
    float a = 0.f, b = 0.f;
#pragma unroll
    for (int k = 0; k < 16; ++k) {
      a = fmaf(Wq[k * 16 + r], qtp[k * 16 + c], a);
      b = fmaf(Hq[k * 16 + r], Rinv[k * 16 + c], b);
    }
    ct[t8] = a;
    Eq[t8] = b;
  } else {
    float d = 0.f, e = 0.f;
#pragma unroll
    for (int k = 0; k < 16; ++k) {
      d = fmaf(OmT[r * 16 + k], Wp[k * 16 + c], d);
      e = fmaf(We[k * 16 + r], OmO[k * 16 + c], e);
    }
    Tt[t8] = d;
    Eo[t8] = e;
  }

  // ---- fused: batch per-t vectors + mmBCD + augA fill + preloads ----
  float ct_c[16], ct_r[16], tt_r[16], wp_r[16];
  float f0_rc, d0_rc;
  __syncthreads();
  {
    float ym[16], ob[16];
#pragma unroll
    for (int k = 0; k < 16; ++k) {
      const float y = obs_s[t8 * 16 + k];
      ym[k] = y - dqv[k];
      ob[k] = peb[k] - y;
    }
    const int i0 = hf * 8;
#pragma unroll
    for (int i2 = 0; i2 < 8; ++i2) {
      const int i = i0 + i2;
      float a = 0.f, b = 0.f;
#pragma unroll
      for (int k = 0; k < 16; ++k) {
        a = fmaf(Eq[i * 16 + k], ym[k], a);
        b = fmaf(Eo[i * 16 + k], ob[k], b);
      }
      hyb[t8 * 16 + i] = a;
      eoy[t8 * 16 + i] = b;
    }
    if (hf) {
      float q = 0.f;
#pragma unroll
      for (int i = 0; i < 16; ++i) {
        float d = 0.f;
#pragma unroll
        for (int k = 0; k < 16; ++k) d = fmaf(OmO[i * 16 + k], ob[k], d);
        q = fmaf(ob[i], d, q);
      }
      qOmO[t8] = q;
    }
  }
  if (!hf) {
    float a = 0.f, b = 0.f;
#pragma unroll
    for (int k = 0; k < 16; ++k) {
      a = fmaf(ct[r * 16 + k], Wq[k * 16 + c], a);
      b = fmaf(Eq[r * 16 + k], Hq[k * 16 + c], b);
    }
    const float f0v = qtp[t8] + b;
    const float fpv = Qp0i[t8] + b;
    fprec[t8] = fpv;
    if (tid < 16) {
      float s = 0.f;
#pragma unroll
      for (int k = 0; k < 16; ++k) s = fmaf(ct[tid * 16 + k], qtb[k], s);
      u0[tid] = s;
    } else if (tid < 32) {
      const int i = tid - 16;
      float s = 0.f;
#pragma unroll
      for (int k = 0; k < 16; ++k) s = fmaf(qtp[i * 16 + k], qtb[k], s);
      v0[i] = s;
    } else if (tid < 48) {
      const int i = tid - 32;
      float s = 0.f;
#pragma unroll
      for (int k = 0; k < 16; ++k) s = fmaf(Om0[i * 16 + k], ppmv[k], s);
      vta[i] = s;
    } else if (tid < 64) {
      const int i = tid - 48;
      float s = 0.f;
#pragma unroll
      for (int k = 0; k < 16; ++k) s = fmaf(OmT[i * 16 + k], ptb[k], s);
      uc_s[i] = s;
    } else if (tid < 80) {
      const int i = tid - 64;
      float s = 0.f;
#pragma unroll
      for (int k = 0; k < 16; ++k) s = fmaf(Tt[k * 16 + i], ptb[k], s);
      wc_s[i] = s;
    }
    // register constants + initial system fill (all from local/prev-phase data)
#pragma unroll
    for (int k = 0; k < 16; ++k) {
      ct_c[k] = ct[k * 16 + c];
      ct_r[k] = ct[k * 16 + r];
      tt_r[k] = Tt[r * 16 + k];
      wp_r[k] = Wp[r * 16 + k];
    }
    f0_rc = f0v;
    d0_rc = a + f0v;
    augA[r * 32 + c] = a + fpv;
    augA[r * 32 + 16 + c] = (r == c) ? 1.f : 0.f;
  } else {
    float e = 0.f, co = 0.f;
#pragma unroll
    for (int k = 0; k < 16; ++k) {
      e = fmaf(Wp[k * 16 + r], Tt[k * 16 + c], e);
      co = fmaf(Eo[r * 16 + k], We[k * 16 + c], co);
    }
    W2n[t8] = e;
    S0[t8] = Om0[t8] + co + e;   // Sw_1
    c3m[t8] = OmT[t8] + co + e;  // c3
  }

  float* Scur = S0;
  float* Snxt = S1;
  float* gcur = gb0;
  float* gnxt = gb1;

  // ================= exact forward t = 1..TF : 3 phases/step =============
#pragma unroll 1
  for (int t = 1; t <= TF; ++t) {
    const int rb = 12 + (t - 1) * 2;
    // ---- phase A: lo GJ0 | w4 Snxt(t>1) | w5 eta0/gb0(t=1) or gnxt(t>1)
    // ----           | w6 cB(t=1) ----
    __syncthreads();
    if (lo) {
      const float det = gj8_phase(augA, augB, 0, tid);
      if (tid == 0) ring[rb + 0] = det;
    } else if (wv == 4 && t > 1) {
      const int ec = lane & 15, er0 = lane >> 4;
      float t1c[16]; ld16(t1c, &t1T[ec * 20]);
#pragma unroll
      for (int q = 0; q < 4; ++q) {
        const int er = er0 + 4 * q;
        const int e = er * 16 + ec;
        float btr[16]; ld16(btr, &bAT[er * 20]);
        Snxt[e] = dot16rr(btr, t1c) - Emat[er * 16 + ec] - Emat[ec * 16 + er] + c3m[e];
      }
    } else if (wv == 5) {
      if (t > 1) {
        if (lane < 16) {
          float bti[16]; ld16(bti, &bAT[lane * 20]);
          float zvv[16]; ld16(zvv, zv);
          gnxt[lane] = -u_t[lane] + eoy[(t - 1) * 16 + lane] + dot16rr(bti, zvv);
        }
      } else {
        if (lane < 16) {
          float s = hyb[lane];
#pragma unroll
          for (int k = 0; k < 16; ++k) s = fmaf(Qp0i[lane * 16 + k], qpmv[k], s);
          eta[lane] = s;
        } else if (lane < 32) {
          const int i = lane - 16;
          gb0[i] = eoy[i] - vta[i];
        }
      }
    } else if (wv == 6 && t == 1) {
      if (lane == 0) {
        float s = 0.f;
#pragma unroll
        for (int k = 0; k < 16; ++k) s = fmaf(ptb[k], uc_s[k], s);
        cB_s = s;
      }
    }
    if (t > 1) {
      float* tp = Scur; Scur = Snxt; Snxt = tp;
      tp = gcur; gcur = gnxt; gnxt = tp;
    }
    // ---- phase B: fused GJ8 + Q1 (in-wave row remap) + ba ----
    __syncthreads();
    if (lo) {
      const float det = gj8_phase(augB, augA, 8, tid);
      if (tid == 0) ring[rb + 1] = det;
      // wave w wrote rows {2w, 2w+1, 2w+8, 2w+9} of augA -> consume in-wave
      const int wrow = ((wv & 3) << 1) + ((lane >> 4) & 1) + ((lane >> 5) << 3);
      const int qc = lane & 15;
      float brow[16]; ld16(brow, &augA[wrow * 32 + 16]);
      const float acc = dot16rr(brow, ct_c);  // ct_c indexed by c == qc
      bAT[qc * 20 + wrow] = acc;
      const float bce = brow[qc];
      trace_acc = fmaf(bce, Scur[wrow * 16 + qc], trace_acc);
      if (t == TF) { bAfN[wrow * 16 + qc] = acc; bcovS[wrow * 16 + qc] = bce; }
      if (qc == 0) {
        float a2 = 0.f;
#pragma unroll
        for (int k = 0; k < 16; ++k) a2 = fmaf(brow[k], eta[k] - u0[k], a2);
        ba[wrow] = a2;
      }
    }
    // ---- phase C: Q2 | w5 eta/u_t/zv | w6 bau0v(t==TF) ----
    __syncthreads();
    if (lo) {
      float bcol[16]; ld16(bcol, &bAT[c * 20]);
      float swr[16];  ld16(swr, &Scur[r * 16]);
      const float sw_rc = swr[c];
      float a1 = 0.f, ae = 0.f, af = 0.f;
#pragma unroll
      for (int k = 0; k < 16; ++k) {
        a1 = fmaf(swr[k], bcol[k], a1);
        ae = fmaf(tt_r[k], bcol[k], ae);
        af = fmaf(ct_r[k], bcol[k], af);
      }
      t1T[c * 20 + r] = a1;
      Emat[tid] = ae;
      fprec[tid] = f0_rc - af;
      augA[r * 32 + c] = d0_rc - af;
      augA[r * 32 + 16 + c] = (r == c) ? 1.f : 0.f;
      if (t == TF) {
        float a0 = 0.f;
#pragma unroll
        for (int k = 0; k < 16; ++k) a0 = fmaf(wp_r[k], bcol[k], a0);
        a0 -= (r == c) ? 1.f : 0.f;
        A0fN[tid] = a0;
        A0fT[c * 20 + r] = a0;
      }
      const float bar = ba[r], bac = ba[c];
      hacc = fmaf(bar * sw_rc, bac, hacc);
      if (r == 0) hacc += 2.f * bac * (gcur[c] + wc_s[c]);
      if (tid == 0) hacc += cB_s + qOmO[t];
    } else if (wv == 5) {
      if (lane < 16) {
        const int i = lane;
        float e = v0[i] + hyb[t * 16 + i];
#pragma unroll
        for (int k = 0; k < 16; ++k) e = fmaf(ct[k * 16 + i], ba[k], e);
        eta[i] = e;
      } else if (lane < 32) {
        const int i = lane - 16;
        float ttrow[16]; ld16(ttrow, &Tt[i * 16]);
        float bav[16]; ld16(bav, ba);
        u_t[i] = uc_s[i] + dot16rr(ttrow, bav);
      } else if (lane < 48) {
        const int i = lane - 32;
        float swrow[16]; ld16(swrow, &Scur[i * 16]);
        float bav[16]; ld16(bav, ba);
        zv[i] = gcur[i] + wc_s[i] + dot16rr(swrow, bav);
      }
    } else if (wv == 6 && t == TF) {
      if (lane < 16) {
        float bc[16]; ld16(bc, &bcovS[lane * 16]);
        float u0v[16]; ld16(u0v, u0);
        bau0v[lane] = dot16rr(bc, u0v);
      }
    }
  }

  // ---- fused: transition (lo) + w/eu batch (hi 256, 16 outputs each) ----
  __syncthreads();
  if (lo) {
    float btr[16]; ld16(btr, &bAT[r * 20]);
    float t1c[16]; ld16(t1c, &t1T[c * 20]);
    Snxt[tid] = dot16rr(btr, t1c) - Emat[r * 16 + c] - Emat[c * 16 + r] + c3m[tid];
    float bcr[16]; ld16(bcr, &bcovS[r * 16]);
    float ctrow[16]; ld16(ctrow, &ct[c * 16]);
    Dm[tid] = dot16rr(bcr, ctrow);  // D[r][c] = sum_k bcov[r][k] ct[c][k]
    ctT[c * 20 + r] = ct[tid];
    WeT[c * 20 + r] = We[tid];
  } else {
    float tmp[16];
#pragma unroll
    for (int k = 0; k < 16; ++k) tmp[k] = v0[k] + hyb[t8 * 16 + k];
#pragma unroll
    for (int i = 0; i < 16; ++i) {
      float s = -bau0v[i];
#pragma unroll
      for (int k = 0; k < 16; ++k) s = fmaf(bcovS[i * 16 + k], tmp[k], s);
      obs_s[t8 * 16 + i] = s;
    }
    if (t8 >= TF) {
#pragma unroll
      for (int i = 0; i < 16; ++i) eoy[t8 * 16 + i] -= uc_s[i];
    }
  }
  { float* tp = Scur; Scur = Snxt; Snxt = tp; }

  // ======= waves 0-3: steady-state chain t=TF+1..255 (16 chunks)
  // ======= wave 4: final fc inversion ; wave 5: S1 + Lyapunov (concurrent)
  __syncthreads();
  if (lo) {
    const int grp = tid >> 4;
    const int i = tid & 15;
    float drow[16], swr[16], ttr[16], bcol[16];
    ld16(drow, &Dm[i * 16]);   // D row i
    ld16(swr, &Scur[i * 16]);  // Sw* row i
    ld16(ttr, &Tt[i * 16]);    // Tt row i
    ld16(bcol, &bAT[i * 20]);  // B col i
    const float wci = wc_s[i];
    float ba_p, zv_p;
    if (grp == 0) {
      ba_p = ba[i]; zv_p = zv[i];
    } else {
      ba_p = 0.f; zv_p = 0.f;
    }
    float haccA = 0.f, haccB = 0.f;
    const int tstart = (TF + 1) + grp * 16 - WUP;
#pragma unroll 1
    for (int j = 0; j < WUP + 16; ++j) {
      if (grp == 0 && j < WUP) continue;
      const int t = tstart + j;
      const int trd = (t > 255) ? 255 : t;
      const float w_c = obs_s[(trd - 1) * 16 + i];
      const float eu_c = eoy[(trd - 1) * 16 + i];
      const float ban = dotshfl16(drow, ba_p) + w_c;
      const float q = dotshfl16(ttr, ba_p);
      const float bz = dotshfl16(bcol, zv_p);
      const float gnew = eu_c - q + bz;
      const float ssw = dotshfl16(swr, ban);
      if (j >= WUP && t <= 255) {
        haccA = fmaf(ban, ssw, haccA);
        haccB = fmaf(ban, gnew + wci, haccB);
      }
      if (t <= 255) {
        zv_p = gnew + wci + ssw;
        ba_p = ban;
      }
    }
    hA256[tid] = haccA;
    hB256[tid] = haccB;
    if (grp == 15) {
      // tail: g_256 = eu_255 - Tt ba_255 + B^T zv_255 ; eta_256
      const float eu_c = eoy[255 * 16 + i];
      gfin[i] = eu_c - dotshfl16(ttr, ba_p) + dotshfl16(bcol, zv_p);
      float ctcol[16]; ld16(ctcol, &ctT[i * 20]);
      etaF[i] = v0[i] + hyb[255 * 16 + i] + dotshfl16(ctcol, ba_p);
    }
  } else if (wv == 4) {
    // final fc = inv(fprec*): wave-local, 2 GJ phases, direct store
    const int ca = lane & 31;
    const int r8 = (lane >> 5) * 8;
#pragma unroll
    for (int h = 0; h < 8; ++h) {
      const int rr = r8 + h;
      augA[rr * 32 + ca] = (ca < 16) ? fprec[rr * 16 + ca] : ((rr == ca - 16) ? 1.f : 0.f);
    }
    const float d0 = gjw_phase(augA, augB, 0, lane);
    const float d1 = gjw_store(augB, fcInv, 1.0f, lane);
    if (lane == 0) { ring[12 + TF * 2] = d0; ring[12 + TF * 2 + 1] = d1; }
  } else if (wv == 5) {
    // S1 (R inits, Bk init) + 4x Lyapunov doubling, wave-local
    const int ec = lane & 15, er0 = lane >> 4;
    {
      float a0c[16]; ld16(a0c, &A0fT[ec * 20]);
      float wec[16]; ld16(wec, &WeT[ec * 20]);
#pragma unroll
      for (int q = 0; q < 4; ++q) {
        const int er = er0 + 4 * q;
        const int e = er * 16 + ec;
        float omtr[16]; ld16(omtr, &OmT[er * 16]);
        float omor[16]; ld16(omor, &OmO[er * 16]);
        const float c1 = dot16rr(omtr, a0c);
        R1m[e] = c1; R1T[ec * 20 + er] = c1;
        const float c2 = dot16rr(omor, wec);
        R2m[e] = c2; R2T[ec * 20 + er] = c2;
        BkA[e] = bAfN[e];
        BkAT[ec * 20 + er] = bAT[ec * 20 + er];
      }
    }
    float* pBk = BkA;  float* pBkT = BkAT;
    float* pBn = BkB;  float* pBnT = BkBT;
#pragma unroll 1
    for (int it = 0; it < 4; ++it) {
      {
        float r1c[16]; ld16(r1c, &R1T[ec * 20]);
        float r2c[16]; ld16(r2c, &R2T[ec * 20]);
        float bkc[16]; ld16(bkc, &pBkT[ec * 20]);
#pragma unroll
        for (int q = 0; q < 4; ++q) {
          const int er = er0 + 4 * q;
          const int e = er * 16 + ec;
          float bkr[16]; ld16(bkr, &pBk[er * 16]);
          T1m[e] = dot16rr(bkr, r1c);
          T2m[e] = dot16rr(bkr, r2c);
          const float bsq = dot16rr(bkr, bkc);
          pBn[e] = bsq;
          pBnT[ec * 20 + er] = bsq;
        }
      }
      {
        float bkc[16]; ld16(bkc, &pBkT[ec * 20]);
#pragma unroll
        for (int q = 0; q < 4; ++q) {
          const int er = er0 + 4 * q;
          const int e = er * 16 + ec;
          float t1r[16]; ld16(t1r, &T1m[er * 16]);
          float t2r[16]; ld16(t2r, &T2m[er * 16]);
          const float n1 = R1m[e] + dot16rr(t1r, bkc);
          const float n2 = R2m[e] + dot16rr(t2r, bkc);
          R1m[e] = n1; R1T[ec * 20 + er] = n1;
          R2m[e] = n2; R2T[ec * 20 + er] = n2;
        }
      }
      { float* tp = pBk; pBk = pBn; pBn = tp; }
      { float* tp = pBkT; pBkT = pBnT; pBnT = tp; }
    }
  }

  // ---- final reduce & output (fm computed locally; Z folded in) ----
  __syncthreads();
  {
    float psum = 0.f;
    if (lo) {
      const float cnt = 255.f - (float)TF;
      psum = trace_acc + hacc;
      psum += cnt * bcovS[tid] * Scur[tid];
      {
        float a0rowc[16]; ld16(a0rowc, &A0fN[c * 16]);
        float r1colr[16]; ld16(r1colr, &R1T[r * 20]);
        float werowc[16]; ld16(werowc, &We[c * 16]);
        float r2colr[16]; ld16(r2colr, &R2T[r * 20]);
        const float zcr = dot16rr(a0rowc, r1colr) + dot16rr(werowc, r2colr);
        psum += fcInv[tid] * zcr;
      }
      {
        float fcr[16]; ld16(fcr, &fcInv[r * 16]);
        float fcc[16]; ld16(fcc, &fcInv[c * 16]);
        float ev[16];  ld16(ev, etaF);
        const float fmr = dot16rr(fcr, ev);
        const float fmc = dot16rr(fcc, ev);
        psum += fmr * (Scur[tid] - W2n[tid]) * fmc;
        if (r == 0) psum += 2.f * fmc * gfin[c];
      }
      psum += hA256[tid] + 2.f * hB256[tid];
      if (tid < 16) psum += ppmv[tid] * vta[tid];
      if (tid > TF || tid == 0) psum += qOmO[tid];
      if (tid == 0) psum += cnt * cB_s;
#pragma unroll 1
      for (int i = tid; i < 12 + TF * 2 + 2; i += 256) {
        float w;
        if (i < 2) w = 255.f;
        else if (i < 4) w = 256.f;
        else if (i < 8) w = 0.f;
        else if (i < 10) w = 1.f;
        else if (i < 12) w = 0.f;
        else if (i < 12 + TF * 2) w = (i >= 12 + (TF - 1) * 2) ? (1.f + cnt) : 1.f;
        else w = 1.f;
        if (w != 0.f) psum -= 0.5f * w * logf(ring[i]);
      }
    }
#pragma unroll
    for (int off = 32; off; off >>= 1) psum += __shfl_down(psum, off, 64);
    if ((tid & 63) == 0) scl[tid >> 6] = psum;
  }
  __syncthreads();
  if (tid == 0) {
    const float base = -16.f * L2P + 255.f * (8.f - 8.f * L2P) + 8.f * L2P + 8.f;
    out[0] = scl[0] + scl[1] + scl[2] + scl[3] + scl[4] + scl[5] + scl[6] + scl[7] + base;
  }
}

extern "C" void kernel_launch(void* const* d_in, const int* in_sizes, int n_in,
                              void* d_out, int out_size, void* d_ws, size_t ws_size,
                              hipStream_t stream) {
  (void)in_sizes; (void)n_in; (void)out_size; (void)d_ws; (void)ws_size;
  lgq_kernel<<<1, 512, 0, stream>>>(
      (const float*)d_in[0], (const float*)d_in[1], (const float*)d_in[2],
      (const float*)d_in[3], (const float*)d_in[4], (const float*)d_in[5],
      (const float*)d_in[6], (const float*)d_in[7], (const float*)d_in[8],
      (const float*)d_in[9], (const float*)d_in[10], (const float*)d_in[11],
      (const float*)d_in[12], (const float*)d_in[13], (const float*)d_in[14],
      (const float*)d_in[15], (const float*)d_in[16], (float*)d_out);
}